// Round 9
// baseline (224.805 us; speedup 1.0000x reference)
//
#include <hip/hip_runtime.h>
#include <hip/hip_bf16.h>
#include <math.h>

#define B_ 2
#define L_ 1024
#define H_ 1024
#define D_ 2048
#define N_ 16
#define R_ 64
#define NCK 32     // chunks per sequence
#define CL 32      // chunk length (NCK*CL == L_)

typedef short short8 __attribute__((ext_vector_type(8)));
typedef float floatx4 __attribute__((ext_vector_type(4)));

__device__ __forceinline__ float siluf(float g) {
    return g / (1.0f + __expf(-g));
}

__device__ __forceinline__ unsigned short f2bf(float f) {
    unsigned int u = __float_as_uint(f);
    u = (u + 0x7fffu + ((u >> 16) & 1u)) >> 16;  // RNE
    return (unsigned short)u;
}

__device__ __forceinline__ float bf2f(unsigned short u) {
    return __uint_as_float(((unsigned int)u) << 16);
}

// async global->LDS, 16B per lane; lds base must be wave-uniform
__device__ __forceinline__ void gl2lds(const unsigned short* g, unsigned short* l) {
    __builtin_amdgcn_global_load_lds(
        (const __attribute__((address_space(1))) unsigned int*)g,
        (__attribute__((address_space(3))) unsigned int*)l, 16, 0, 0);
}

// ---------------- fused fp32 -> bf16 convert for all 5 static tensors ----------------
#define Q0 524288    // hs        2048*1024 /4
#define Q1 1572864   // + W_in    4096*1024 /4
#define Q2 2097152   // + W_out   1024*2048 /4
#define Q3 2146304   // + W_x     96*2048   /4
#define Q4 2179072   // + W_dt    2048*64   /4
__global__ __launch_bounds__(256) void cvt_all(
    const float* __restrict__ i0, const float* __restrict__ i1,
    const float* __restrict__ i2, const float* __restrict__ i3,
    const float* __restrict__ i4,
    unsigned short* __restrict__ o0, unsigned short* __restrict__ o1,
    unsigned short* __restrict__ o2, unsigned short* __restrict__ o3,
    unsigned short* __restrict__ o4)
{
    int q = blockIdx.x * 256 + threadIdx.x;
    if (q >= Q4) return;
    const float* in; unsigned short* out; int base;
    if (q < Q0)      { in = i0; out = o0; base = 0; }
    else if (q < Q1) { in = i1; out = o1; base = Q0; }
    else if (q < Q2) { in = i2; out = o2; base = Q1; }
    else if (q < Q3) { in = i3; out = o3; base = Q2; }
    else             { in = i4; out = o4; base = Q3; }
    int i = (q - base) * 4;
    float4 v = *(const float4*)(in + i);
    ushort4 o;
    o.x = f2bf(v.x); o.y = f2bf(v.y); o.z = f2bf(v.z); o.w = f2bf(v.w);
    *(ushort4*)(out + i) = o;
}

// ---------------- fat-wave GEMM: C = A[M,K] @ B[N,K]^T, 128x128 tile, BK=64 -------
// 256 threads, 4 waves as 2x2, each wave 64x64 output (4x4 frags of 16x16x32).
// FLOP per LDS byte = 32. Double-buffered LDS (64 KB), depth-1 prefetch, counted
// vmcnt(8), raw s_barrier. Rule-21 swizzle: LDS linear, source col-slot and read
// col-slot both XOR (row&7) over the 8 16B slots. N multiple of 128, K mult of 64.
// EPI: 0 = split-K partial store C[z*partStride + m*ldc + n],
//      4 = proj: n<2048 -> C[m][n] (xpre); n>=2048 -> C2[m][n-2048] (gate)
template<int EPI>
__global__ __launch_bounds__(256) void gemm128(
    const unsigned short* __restrict__ A, const unsigned short* __restrict__ Bm,
    float* __restrict__ C, int K, int ldc, int kChunk,
    size_t partStride, float* __restrict__ C2)
{
    __shared__ unsigned short As[2][128 * 64];
    __shared__ unsigned short Bs[2][128 * 64];
    const int tid  = threadIdx.x;
    const int lane = tid & 63;
    const int wave = tid >> 6;
    const int wm = (wave >> 1) * 64;
    const int wn = (wave & 1) * 64;
    const int lr   = lane & 15;
    const int quad = lane >> 4;
    const int m0 = blockIdx.y * 128;
    const int n0 = blockIdx.x * 128;
    const int k0 = blockIdx.z * kChunk;

    // staging: per gl2lds call, wave w covers LDS rows w*8..w*8+7 (lane>>3 = row-in-8,
    // lane&7 = col slot). Source col-slot XOR'd by (row&7)=rowIn8 (rule 21).
    const int rowIn8 = lane >> 3;
    const int colSw  = ((lane & 7) ^ rowIn8) * 8;
    const int srow   = wave * 8 + rowIn8;               // 0..31
    const size_t aoff0 = (size_t)(m0 + srow +  0) * K + colSw;
    const size_t aoff1 = (size_t)(m0 + srow + 32) * K + colSw;
    const size_t aoff2 = (size_t)(m0 + srow + 64) * K + colSw;
    const size_t aoff3 = (size_t)(m0 + srow + 96) * K + colSw;
    const size_t boff0 = (size_t)(n0 + srow +  0) * K + colSw;
    const size_t boff1 = (size_t)(n0 + srow + 32) * K + colSw;
    const size_t boff2 = (size_t)(n0 + srow + 64) * K + colSw;
    const size_t boff3 = (size_t)(n0 + srow + 96) * K + colSw;
    // read slots: k-slice0 -> slot quad, k-slice1 -> slot 4+quad, both ^ (lr&7)
    const int rq0 = ((quad) ^ (lr & 7)) * 8;
    const int rq1 = rq0 ^ 32;

    floatx4 acc[4][4];
#pragma unroll
    for (int mi = 0; mi < 4; ++mi)
#pragma unroll
        for (int ni = 0; ni < 4; ++ni)
            acc[mi][ni] = (floatx4){0.f, 0.f, 0.f, 0.f};

#define STG(buf, kt)                                                    \
    do {                                                                \
        gl2lds(A + aoff0 + (kt), &As[buf][(0  + wave * 8) * 64]);       \
        gl2lds(A + aoff1 + (kt), &As[buf][(32 + wave * 8) * 64]);       \
        gl2lds(A + aoff2 + (kt), &As[buf][(64 + wave * 8) * 64]);       \
        gl2lds(A + aoff3 + (kt), &As[buf][(96 + wave * 8) * 64]);       \
        gl2lds(Bm + boff0 + (kt), &Bs[buf][(0  + wave * 8) * 64]);      \
        gl2lds(Bm + boff1 + (kt), &Bs[buf][(32 + wave * 8) * 64]);      \
        gl2lds(Bm + boff2 + (kt), &Bs[buf][(64 + wave * 8) * 64]);      \
        gl2lds(Bm + boff3 + (kt), &Bs[buf][(96 + wave * 8) * 64]);      \
    } while (0)

    STG(0, k0);

    const int nt = kChunk >> 6;
    for (int t = 0; t < nt; ++t) {
        const int cur = t & 1;
        if (t + 1 < nt) {
            STG(cur ^ 1, k0 + (t + 1) * 64);
            asm volatile("s_waitcnt vmcnt(8)" ::: "memory");  // tile t landed; t+1 in flight
        } else {
            asm volatile("s_waitcnt vmcnt(0)" ::: "memory");
        }
        __builtin_amdgcn_s_barrier();          // all waves see tile t in LDS
        __builtin_amdgcn_sched_barrier(0);     // pin: no LDS reads hoisted above

        short8 a0f[4], a1f[4], b0f[4], b1f[4];
#pragma unroll
        for (int mi = 0; mi < 4; ++mi) {
            a0f[mi] = *(const short8*)&As[cur][(wm + mi * 16 + lr) * 64 + rq0];
            a1f[mi] = *(const short8*)&As[cur][(wm + mi * 16 + lr) * 64 + rq1];
        }
#pragma unroll
        for (int ni = 0; ni < 4; ++ni) {
            b0f[ni] = *(const short8*)&Bs[cur][(wn + ni * 16 + lr) * 64 + rq0];
            b1f[ni] = *(const short8*)&Bs[cur][(wn + ni * 16 + lr) * 64 + rq1];
        }
#pragma unroll
        for (int mi = 0; mi < 4; ++mi)
#pragma unroll
            for (int ni = 0; ni < 4; ++ni)
                acc[mi][ni] = __builtin_amdgcn_mfma_f32_16x16x32_bf16(
                    a0f[mi], b0f[ni], acc[mi][ni], 0, 0, 0);
#pragma unroll
        for (int mi = 0; mi < 4; ++mi)
#pragma unroll
            for (int ni = 0; ni < 4; ++ni)
                acc[mi][ni] = __builtin_amdgcn_mfma_f32_16x16x32_bf16(
                    a1f[mi], b1f[ni], acc[mi][ni], 0, 0, 0);

        asm volatile("s_waitcnt lgkmcnt(0)" ::: "memory");  // this wave's reads retired
        __builtin_amdgcn_s_barrier();          // safe for next stage to overwrite cur
    }
#undef STG

    float* Cz = C + (size_t)blockIdx.z * partStride;
#pragma unroll
    for (int mi = 0; mi < 4; ++mi)
#pragma unroll
        for (int ni = 0; ni < 4; ++ni) {
            const int rr = m0 + wm + mi * 16 + quad * 4;
            const int cc = n0 + wn + ni * 16 + lr;
            if (EPI == 4) {
                if (cc < 2048) {
#pragma unroll
                    for (int r = 0; r < 4; ++r)
                        C[(size_t)(rr + r) * 2048 + cc] = acc[mi][ni][r];
                } else {
#pragma unroll
                    for (int r = 0; r < 4; ++r)
                        C2[(size_t)(rr + r) * 2048 + (cc - 2048)] = acc[mi][ni][r];
                }
            } else {
#pragma unroll
                for (int r = 0; r < 4; ++r)
                    Cz[(size_t)(rr + r) * ldc + cc] = acc[mi][ni][r];
            }
        }
}

// ---------------- narrow GEMM (ssm): C = A[M,K] @ B[N,K]^T, 64x128 tile, BK=64 ----
// 4 waves as 2m x 2n, wave 32x64; counted vmcnt(6); row-clamped B (N=96).
__global__ __launch_bounds__(256) void gemm_ssm(
    const unsigned short* __restrict__ A, const unsigned short* __restrict__ Bm,
    float* __restrict__ C, int K, int Ncols, int ldc, int kChunk, int nMax,
    size_t partStride)
{
    __shared__ unsigned short As[2][64 * 64];
    __shared__ unsigned short Bs[2][128 * 64];
    const int tid  = threadIdx.x;
    const int lane = tid & 63;
    const int wave = tid >> 6;
    const int wm = (wave >> 1) * 32;
    const int wn = (wave & 1) * 64;
    const int lr   = lane & 15;
    const int quad = lane >> 4;
    const int m0 = blockIdx.y * 64;
    const int n0 = blockIdx.x * 128;
    const int k0 = blockIdx.z * kChunk;

    const int rowIn8 = lane >> 3;
    const int colSw  = ((lane & 7) ^ rowIn8) * 8;
    const size_t aoff0 = (size_t)(m0 + 0  + wave * 8 + rowIn8) * K + colSw;
    const size_t aoff1 = (size_t)(m0 + 32 + wave * 8 + rowIn8) * K + colSw;
    const size_t boff0 = (size_t)min(n0 + 0  + wave * 8 + rowIn8, nMax - 1) * K + colSw;
    const size_t boff1 = (size_t)min(n0 + 32 + wave * 8 + rowIn8, nMax - 1) * K + colSw;
    const size_t boff2 = (size_t)min(n0 + 64 + wave * 8 + rowIn8, nMax - 1) * K + colSw;
    const size_t boff3 = (size_t)min(n0 + 96 + wave * 8 + rowIn8, nMax - 1) * K + colSw;
    const int rq0 = ((quad) ^ (lr & 7)) * 8;
    const int rq1 = rq0 ^ 32;

    floatx4 acc[2][4];
#pragma unroll
    for (int mi = 0; mi < 2; ++mi)
#pragma unroll
        for (int ni = 0; ni < 4; ++ni)
            acc[mi][ni] = (floatx4){0.f, 0.f, 0.f, 0.f};

#define STAGE(buf, kt)                                                   \
    do {                                                                 \
        gl2lds(A + aoff0 + (kt), &As[buf][(0  + wave * 8) * 64]);        \
        gl2lds(A + aoff1 + (kt), &As[buf][(32 + wave * 8) * 64]);        \
        gl2lds(Bm + boff0 + (kt), &Bs[buf][(0   + wave * 8) * 64]);      \
        gl2lds(Bm + boff1 + (kt), &Bs[buf][(32  + wave * 8) * 64]);      \
        gl2lds(Bm + boff2 + (kt), &Bs[buf][(64  + wave * 8) * 64]);      \
        gl2lds(Bm + boff3 + (kt), &Bs[buf][(96  + wave * 8) * 64]);      \
    } while (0)

    STAGE(0, k0);

    const int nt = kChunk >> 6;
    for (int t = 0; t < nt; ++t) {
        const int cur = t & 1;
        if (t + 1 < nt) {
            STAGE(cur ^ 1, k0 + (t + 1) * 64);
            asm volatile("s_waitcnt vmcnt(6)" ::: "memory");
        } else {
            asm volatile("s_waitcnt vmcnt(0)" ::: "memory");
        }
        __builtin_amdgcn_s_barrier();
        __builtin_amdgcn_sched_barrier(0);

        short8 a0[2], a1[2], b0[4], b1[4];
#pragma unroll
        for (int mi = 0; mi < 2; ++mi) {
            a0[mi] = *(const short8*)&As[cur][(wm + mi * 16 + lr) * 64 + rq0];
            a1[mi] = *(const short8*)&As[cur][(wm + mi * 16 + lr) * 64 + rq1];
        }
#pragma unroll
        for (int ni = 0; ni < 4; ++ni) {
            b0[ni] = *(const short8*)&Bs[cur][(wn + ni * 16 + lr) * 64 + rq0];
            b1[ni] = *(const short8*)&Bs[cur][(wn + ni * 16 + lr) * 64 + rq1];
        }
#pragma unroll
        for (int mi = 0; mi < 2; ++mi)
#pragma unroll
            for (int ni = 0; ni < 4; ++ni)
                acc[mi][ni] = __builtin_amdgcn_mfma_f32_16x16x32_bf16(
                    a0[mi], b0[ni], acc[mi][ni], 0, 0, 0);
#pragma unroll
        for (int mi = 0; mi < 2; ++mi)
#pragma unroll
            for (int ni = 0; ni < 4; ++ni)
                acc[mi][ni] = __builtin_amdgcn_mfma_f32_16x16x32_bf16(
                    a1[mi], b1[ni], acc[mi][ni], 0, 0, 0);

        asm volatile("s_waitcnt lgkmcnt(0)" ::: "memory");
        __builtin_amdgcn_s_barrier();
    }
#undef STAGE

    float* Cz = C + (size_t)blockIdx.z * partStride;
#pragma unroll
    for (int mi = 0; mi < 2; ++mi)
#pragma unroll
        for (int ni = 0; ni < 4; ++ni) {
            const int rr = m0 + wm + mi * 16 + quad * 4;
            const int cc = n0 + wn + ni * 16 + lr;
            if (cc >= Ncols) continue;
#pragma unroll
            for (int r = 0; r < 4; ++r)
                Cz[(size_t)(rr + r) * ldc + cc] = acc[mi][ni][r];
        }
}

// ---------------- reduce 8 ssm partials -> ssm_p[m][96] + sp64_bf[m][64] ----------------
__global__ __launch_bounds__(256) void reduce_ssm(
    const float* __restrict__ P, float* __restrict__ ssm_p,
    unsigned short* __restrict__ sp64)
{
    const int q = blockIdx.x * 256 + threadIdx.x;    // 2048*24 quads
    const int m = q / 24;
    const int c = (q - m * 24) * 4;
    const size_t idx = (size_t)m * 96 + c;
    float4 s = make_float4(0.f, 0.f, 0.f, 0.f);
#pragma unroll
    for (int z = 0; z < 8; ++z) {
        float4 v = *(const float4*)(P + (size_t)z * (2048 * 96) + idx);
        s.x += v.x; s.y += v.y; s.z += v.z; s.w += v.w;
    }
    *(float4*)(ssm_p + idx) = s;
    if (c < 64) {
        ushort4 o;
        o.x = f2bf(s.x); o.y = f2bf(s.y); o.z = f2bf(s.z); o.w = f2bf(s.w);
        *(ushort4*)(sp64 + (size_t)m * 64 + c) = o;
    }
}

// ---------------- reduce 2 out partials -> out[m][h] ----------------
__global__ __launch_bounds__(256) void reduce_out(
    const float* __restrict__ P, float* __restrict__ out)
{
    const size_t i = ((size_t)blockIdx.x * 256 + threadIdx.x) * 4;  // 2048*1024 total
    float4 a = *(const float4*)(P + i);
    float4 b = *(const float4*)(P + 2097152 + i);
    *(float4*)(out + i) = make_float4(a.x + b.x, a.y + b.y, a.z + b.z, a.w + b.w);
}

// ---------------- dedicated dt GEMM: dt[m][d] = softplus(sp64 @ W_dt^T + b) -------
__global__ __launch_bounds__(256) void dt_gemm(
    const unsigned short* __restrict__ A,   // sp64_bf [2048 m][64]
    const unsigned short* __restrict__ Bm,  // W_dt_bf [2048 d][64]
    float* __restrict__ C,                  // dt [2048 m][2048 d]
    const float* __restrict__ bias)         // b_dt [2048]
{
    __shared__ unsigned short As[64 * 72];
    __shared__ unsigned short Bs[64 * 72];
    const int tid = threadIdx.x;
    const int lane = tid & 63;
    const int wave = tid >> 6;
    const int lr = lane & 15;
    const int quad = lane >> 4;
    const int n0 = blockIdx.x * 64;
    const int m0 = blockIdx.y * 64;

    {
        const int row = tid >> 3;
        const int cq = (tid & 7) * 8;
        uint4 a0 = *(const uint4*)(A + (size_t)(m0 + row) * 64 + cq);
        uint4 a1 = *(const uint4*)(A + (size_t)(m0 + 32 + row) * 64 + cq);
        uint4 b0 = *(const uint4*)(Bm + (size_t)(n0 + row) * 64 + cq);
        uint4 b1 = *(const uint4*)(Bm + (size_t)(n0 + 32 + row) * 64 + cq);
        *(uint4*)&As[row * 72 + cq] = a0;
        *(uint4*)&As[(32 + row) * 72 + cq] = a1;
        *(uint4*)&Bs[row * 72 + cq] = b0;
        *(uint4*)&Bs[(32 + row) * 72 + cq] = b1;
    }
    __syncthreads();

    floatx4 acc[4];
#pragma unroll
    for (int ni = 0; ni < 4; ++ni) acc[ni] = (floatx4){0.f, 0.f, 0.f, 0.f};

#pragma unroll
    for (int kt = 0; kt < 64; kt += 32) {
        short8 af = *(const short8*)&As[(wave * 16 + lr) * 72 + kt + quad * 8];
#pragma unroll
        for (int ni = 0; ni < 4; ++ni) {
            short8 bf = *(const short8*)&Bs[(ni * 16 + lr) * 72 + kt + quad * 8];
            acc[ni] = __builtin_amdgcn_mfma_f32_16x16x32_bf16(af, bf, acc[ni], 0, 0, 0);
        }
    }

    const int rr = m0 + wave * 16 + quad * 4;
#pragma unroll
    for (int ni = 0; ni < 4; ++ni) {
        const int cc = n0 + ni * 16 + lr;
        const float bv = bias[cc];
#pragma unroll
        for (int r = 0; r < 4; ++r) {
            const float z = acc[ni][r] + bv;
            const float spv = fmaxf(z, 0.f) + __logf(1.f + __expf(-fabsf(z)));
            C[(size_t)(rr + r) * 2048 + cc] = spv;
        }
    }
}

// ---------------- causal depthwise conv (K=4) + bias + SiLU, m-major f32 in ------
// xpre[m][d] staged through LDS: coalesced global reads, conflict-free LDS reads.
__global__ __launch_bounds__(256) void conv_silu_kernel(
    const float* __restrict__ xpre, const float* __restrict__ conv_w,
    const float* __restrict__ conv_b, unsigned short* __restrict__ x_bf)
{
    __shared__ float inT[67][64];            // rows r <-> l = lt0 + r - 3
    __shared__ unsigned short tile[64][72];  // out staging for coalesced store
    const int t = threadIdx.x;
    const int d0 = blockIdx.x * 64;
    const int lt0 = blockIdx.y * 64;
    const int b = blockIdx.z;

    {
        const int r = t >> 2;          // 0..63
        const int q = (t & 3) * 16;    // 0,16,32,48
        const int l = lt0 + r - 3;
        if (l >= 0) {
            const float* src = xpre + ((size_t)(b * 1024 + l)) * 2048 + d0 + q;
            *(float4*)&inT[r][q + 0]  = *(const float4*)(src + 0);
            *(float4*)&inT[r][q + 4]  = *(const float4*)(src + 4);
            *(float4*)&inT[r][q + 8]  = *(const float4*)(src + 8);
            *(float4*)&inT[r][q + 12] = *(const float4*)(src + 12);
        } else {
            float4 z4 = make_float4(0.f, 0.f, 0.f, 0.f);
            *(float4*)&inT[r][q + 0]  = z4;
            *(float4*)&inT[r][q + 4]  = z4;
            *(float4*)&inT[r][q + 8]  = z4;
            *(float4*)&inT[r][q + 12] = z4;
        }
        if (t < 12) {
            const int r2 = 64 + (t >> 2);      // 64..66
            const int l2 = lt0 + r2 - 3;       // = lt0 + 61..63, always >= 0
            const float* src = xpre + ((size_t)(b * 1024 + l2)) * 2048 + d0 + q;
            *(float4*)&inT[r2][q + 0]  = *(const float4*)(src + 0);
            *(float4*)&inT[r2][q + 4]  = *(const float4*)(src + 4);
            *(float4*)&inT[r2][q + 8]  = *(const float4*)(src + 8);
            *(float4*)&inT[r2][q + 12] = *(const float4*)(src + 12);
        }
    }
    __syncthreads();

    const int dl = t & 63;
    const int seg = t >> 6;
    const int d = d0 + dl;
    const float w0 = conv_w[d * 4 + 0], w1 = conv_w[d * 4 + 1];
    const float w2 = conv_w[d * 4 + 2], w3 = conv_w[d * 4 + 3];
    const float bias = conv_b[d];

    float p[19];
#pragma unroll
    for (int j = 0; j < 19; ++j) p[j] = inT[seg * 16 + j][dl];
#pragma unroll
    for (int j = 0; j < 16; ++j) {
        float v = siluf(bias + w0 * p[j] + w1 * p[j + 1] + w2 * p[j + 2] + w3 * p[j + 3]);
        tile[seg * 16 + j][dl] = f2bf(v);
    }
    __syncthreads();

    const int ml = t >> 2;
    const int c = t & 3;
    short8 s0 = *(const short8*)&tile[ml][c * 16];
    short8 s1 = *(const short8*)&tile[ml][c * 16 + 8];
    unsigned short* dst = x_bf + (size_t)(b * 1024 + lt0 + ml) * 2048 + d0 + c * 16;
    *(short8*)dst = s0;
    *(short8*)(dst + 8) = s1;
}

// ---------------- scan pass 1: per-chunk H[n] (from h=0) + dt-sum scalar ----------------
__global__ __launch_bounds__(256) void scan_p1(
    const float* __restrict__ dt, const unsigned short* __restrict__ x_bf,
    const float* __restrict__ sp, const float* __restrict__ A_log,
    float* __restrict__ Dts, float* __restrict__ Hch)
{
    __shared__ float sB[CL][16];
    const int tid = threadIdx.x;
    const int d = blockIdx.x * 256 + tid;
    const int ck = blockIdx.y;
    const int b = blockIdx.z;
    const int mb = b * 1024 + ck * CL;

    if (tid < CL * 4) {
        int row = tid >> 2, q = (tid & 3) * 4;
        *(float4*)&sB[row][q] = *(const float4*)(sp + (size_t)(mb + row) * 96 + 64 + q);
    }
    float An2[16];
    {
        const float* al = A_log + d * 16;
#pragma unroll
        for (int j = 0; j < 16; j += 4) {
            float4 a4 = *(const float4*)(al + j);
            An2[j + 0] = -__expf(a4.x) * 1.44269504f;
            An2[j + 1] = -__expf(a4.y) * 1.44269504f;
            An2[j + 2] = -__expf(a4.z) * 1.44269504f;
            An2[j + 3] = -__expf(a4.w) * 1.44269504f;
        }
    }
    __syncthreads();

    float h[16];
#pragma unroll
    for (int n = 0; n < 16; ++n) h[n] = 0.f;
    float dts = 0.f;

    for (int l = 0; l < CL; ++l) {
        const size_t off = (size_t)(mb + l) * 2048 + d;
        const float dtv = dt[off];
        const float xv = bf2f(x_bf[off]);
        const float u = dtv * xv;
        dts += dtv;
        float4 B0 = *(const float4*)&sB[l][0];
        float4 B1 = *(const float4*)&sB[l][4];
        float4 B2 = *(const float4*)&sB[l][8];
        float4 B3 = *(const float4*)&sB[l][12];
        float Bv[16] = {B0.x, B0.y, B0.z, B0.w, B1.x, B1.y, B1.z, B1.w,
                        B2.x, B2.y, B2.z, B2.w, B3.x, B3.y, B3.z, B3.w};
#pragma unroll
        for (int n = 0; n < 16; ++n) {
            const float dA = __builtin_amdgcn_exp2f(dtv * An2[n]);
            h[n] = fmaf(dA, h[n], Bv[n] * u);
        }
    }

    const size_t cb = (size_t)(b * NCK + ck) * 2048 + d;
    Dts[cb] = dts;
    const size_t base = cb * 16;
#pragma unroll
    for (int j = 0; j < 16; j += 4)
        *(float4*)(Hch + base + j) = make_float4(h[j], h[j + 1], h[j + 2], h[j + 3]);
}

// ---------------- scan combine: serial over chunks; recompute P from dts ------
__global__ __launch_bounds__(256) void scan_combine(
    const float* __restrict__ Dts, const float* __restrict__ Hch,
    const float* __restrict__ A_log, float* __restrict__ Hin)
{
    const int flat = blockIdx.x * 256 + threadIdx.x;   // 2*2048*16
    const int dn = flat & 32767;
    const int b = flat >> 15;
    const int d = dn >> 4;
    const float An2 = -__expf(A_log[dn]) * 1.44269504f;
    float hin = 0.f;
#pragma unroll 4
    for (int ck = 0; ck < NCK; ++ck) {
        const size_t cb = (size_t)(b * NCK + ck) * 2048 + d;
        const float p = __builtin_amdgcn_exp2f(Dts[cb] * An2);
        const size_t a = ((size_t)(b * NCK + ck) << 15) + dn;
        const float hc = Hch[a];
        Hin[a] = hin;
        hin = fmaf(p, hin, hc);
    }
}

// ---------------- scan pass 2: rescan with h_in + fused gating -> y_bf[m][d] ----
__global__ __launch_bounds__(256) void scan_p2(
    const float* __restrict__ dt, const unsigned short* __restrict__ x_bf,
    const float* __restrict__ gate, const float* __restrict__ sp,
    const float* __restrict__ A_log, const float* __restrict__ Dp,
    const float* __restrict__ Hin, unsigned short* __restrict__ y_bf)
{
    __shared__ float sBC[CL][32];
    const int tid = threadIdx.x;
    const int d = blockIdx.x * 256 + tid;
    const int ck = blockIdx.y;
    const int b = blockIdx.z;
    const int mb = b * 1024 + ck * CL;

    {
        int row = tid >> 3, q = (tid & 7) * 4;
        *(float4*)&sBC[row][q] = *(const float4*)(sp + (size_t)(mb + row) * 96 + 64 + q);
    }
    float An2[16];
    {
        const float* al = A_log + d * 16;
#pragma unroll
        for (int j = 0; j < 16; j += 4) {
            float4 a4 = *(const float4*)(al + j);
            An2[j + 0] = -__expf(a4.x) * 1.44269504f;
            An2[j + 1] = -__expf(a4.y) * 1.44269504f;
            An2[j + 2] = -__expf(a4.z) * 1.44269504f;
            An2[j + 3] = -__expf(a4.w) * 1.44269504f;
        }
    }
    float h[16];
    {
        const size_t base = ((size_t)(b * NCK + ck) * 2048 + d) * 16;
#pragma unroll
        for (int j = 0; j < 16; j += 4) {
            float4 hv = *(const float4*)(Hin + base + j);
            h[j] = hv.x; h[j + 1] = hv.y; h[j + 2] = hv.z; h[j + 3] = hv.w;
        }
    }
    const float Dv = Dp[d];
    __syncthreads();

    for (int l = 0; l < CL; ++l) {
        const size_t off = (size_t)(mb + l) * 2048 + d;
        const float dtv = dt[off];
        const float xv = bf2f(x_bf[off]);
        const float gv = gate[off];
        const float u = dtv * xv;
        float4 B0 = *(const float4*)&sBC[l][0];
        float4 B1 = *(const float4*)&sBC[l][4];
        float4 B2 = *(const float4*)&sBC[l][8];
        float4 B3 = *(const float4*)&sBC[l][12];
        float Bv[16] = {B0.x, B0.y, B0.z, B0.w, B1.x, B1.y, B1.z, B1.w,
                        B2.x, B2.y, B2.z, B2.w, B3.x, B3.y, B3.z, B3.w};
#pragma unroll
        for (int n = 0; n < 16; ++n) {
            const float dA = __builtin_amdgcn_exp2f(dtv * An2[n]);
            h[n] = fmaf(dA, h[n], Bv[n] * u);
        }
        float4 C0 = *(const float4*)&sBC[l][16];
        float4 C1 = *(const float4*)&sBC[l][20];
        float4 C2 = *(const float4*)&sBC[l][24];
        float4 C3 = *(const float4*)&sBC[l][28];
        float Cv[16] = {C0.x, C0.y, C0.z, C0.w, C1.x, C1.y, C1.z, C1.w,
                        C2.x, C2.y, C2.z, C2.w, C3.x, C3.y, C3.z, C3.w};
        float p = 0.f;
#pragma unroll
        for (int n = 0; n < 16; ++n)
            p = fmaf(h[n], Cv[n], p);
        y_bf[off] = f2bf(fmaf(xv, Dv, p) * siluf(gv));
    }
}

extern "C" void kernel_launch(void* const* d_in, const int* in_sizes, int n_in,
                              void* d_out, int out_size, void* d_ws, size_t ws_size,
                              hipStream_t stream)
{
    const float* hs     = (const float*)d_in[0];
    const float* W_in   = (const float*)d_in[1];
    const float* conv_w = (const float*)d_in[2];
    const float* conv_b = (const float*)d_in[3];
    const float* W_x    = (const float*)d_in[4];
    const float* W_dt   = (const float*)d_in[5];
    const float* b_dt   = (const float*)d_in[6];
    const float* A_log  = (const float*)d_in[7];
    const float* Dp     = (const float*)d_in[8];
    const float* W_out  = (const float*)d_in[9];
    float* out = (float*)d_out;

    // workspace (~78 MB live) with overlays
    float* ws    = (float*)d_ws;
    float* gate  = ws;                               // [2048 m][2048 d] f32
    float* dtb   = gate + (size_t)4194304;           // [2048 m][2048 d] f32
    float* xpre  = dtb + (size_t)4194304;            // [2048 m][2048 d] f32 (dead after conv)
    float* ssm_p = xpre + (size_t)4194304;           // [2048 m][96] f32
    unsigned short* hs_bf    = (unsigned short*)(ssm_p + 196608);   // 2048*1024
    unsigned short* W_in_bf  = hs_bf + (size_t)2097152;             // 4096*1024
    unsigned short* W_out_bf = W_in_bf + (size_t)4194304;           // 1024*2048
    unsigned short* W_x_bf   = W_out_bf + (size_t)2097152;          // 96*2048
    unsigned short* W_dt_bf  = W_x_bf + (size_t)196608;             // 2048*64
    unsigned short* sp64_bf  = W_dt_bf + (size_t)131072;            // 2048*64
    unsigned short* x_bf     = sp64_bf + (size_t)131072;            // [2048 m][2048 d]
    float* Dts  = (float*)(x_bf + (size_t)4194304);   // [2*32][2048] dt-sums (0.5 MB)
    float* P1   = xpre;                               // overlay: ssm partials 8*2048*96
    float* Hin  = xpre;                               // overlay after reduce_ssm: 2*32*2048*16
    float* Hch  = xpre + (size_t)2097152;             // overlay
    float* Pout = gate;                               // overlay after scan_p2: 2*2048*1024
    unsigned short* y_bf = hs_bf;                     // overlay (hs_bf+W_in_bf dead)

    const int M = B_ * L_;  // 2048

    // 0. fused fp32 -> bf16 converts (hs, W_in, W_out, W_x, W_dt)
    cvt_all<<<(Q4 + 255) / 256, 256, 0, stream>>>(
        hs, W_in, W_out, W_x, W_dt, hs_bf, W_in_bf, W_out_bf, W_x_bf, W_dt_bf);

    // 1. proj GEMM: 128x128 fat-wave tile, BK=64 -> 512 blocks, nt=16
    gemm128<4><<<dim3(4096 / 128, M / 128, 1), 256, 0, stream>>>(
        hs_bf, W_in_bf, xpre, 1024, 2048, 1024, 0, gate);

    // 2. conv + SiLU (m-major in via LDS stage) -> x_bf[m][d]
    conv_silu_kernel<<<dim3(D_ / 64, L_ / 64, B_), 256, 0, stream>>>(
        xpre, conv_w, conv_b, x_bf);

    // 3. ssm partials: P1[z][m][96] = x @ W_x^T (K-chunk 256, 8 splits, nt=4)
    gemm_ssm<<<dim3(1, M / 64, 8), 256, 0, stream>>>(
        x_bf, W_x_bf, P1, 2048, 96, 96, 256, 96, (size_t)2048 * 96);

    // 3b. reduce 8 partials -> ssm_p[m][96] + sp64_bf[m][64]
    reduce_ssm<<<(2048 * 24) / 256, 256, 0, stream>>>(P1, ssm_p, sp64_bf);

    // 4. dt[m][d] = softplus(dt_lr @ W_dt^T + b_dt[d]) — dedicated 64x64 kernel
    dt_gemm<<<dim3(2048 / 64, 2048 / 64), 256, 0, stream>>>(
        sp64_bf, W_dt_bf, dtb, b_dt);

    // 5. scan: pass1 -> combine (P recomputed from dts) -> pass2 (writes y_bf[m][d])
    scan_p1<<<dim3(D_ / 256, NCK, B_), 256, 0, stream>>>(
        dtb, x_bf, ssm_p, A_log, Dts, Hch);
    scan_combine<<<(B_ * D_ * 16) / 256, 256, 0, stream>>>(Dts, Hch, A_log, Hin);
    scan_p2<<<dim3(D_ / 256, NCK, B_), 256, 0, stream>>>(
        dtb, x_bf, gate, ssm_p, A_log, Dp, Hin, y_bf);

    // 6. out partials: 128x128 fat-wave, K-chunk 1024, 2 splits -> 256 blocks, nt=16
    gemm128<0><<<dim3(1024 / 128, M / 128, 2), 256, 0, stream>>>(
        y_bf, W_out_bf, Pout, 2048, 1024, 1024, (size_t)2048 * 1024, nullptr);

    // 6b. reduce 2 partials -> out
    reduce_out<<<(2048 * 1024 / 4) / 256, 256, 0, stream>>>(Pout, out);
}

// Round 10
// 220.000 us; speedup vs baseline: 1.0218x; 1.0218x over previous
//
#include <hip/hip_runtime.h>
#include <hip/hip_bf16.h>
#include <math.h>

#define B_ 2
#define L_ 1024
#define H_ 1024
#define D_ 2048
#define N_ 16
#define R_ 64
#define NCK 32     // chunks per sequence
#define CL 32      // chunk length (NCK*CL == L_)

typedef short short8 __attribute__((ext_vector_type(8)));
typedef float floatx4 __attribute__((ext_vector_type(4)));

__device__ __forceinline__ float siluf(float g) {
    return g / (1.0f + __expf(-g));
}

__device__ __forceinline__ unsigned short f2bf(float f) {
    unsigned int u = __float_as_uint(f);
    u = (u + 0x7fffu + ((u >> 16) & 1u)) >> 16;  // RNE
    return (unsigned short)u;
}

__device__ __forceinline__ float bf2f(unsigned short u) {
    return __uint_as_float(((unsigned int)u) << 16);
}

// async global->LDS, 16B per lane; lds base must be wave-uniform
__device__ __forceinline__ void gl2lds(const unsigned short* g, unsigned short* l) {
    __builtin_amdgcn_global_load_lds(
        (const __attribute__((address_space(1))) unsigned int*)g,
        (__attribute__((address_space(3))) unsigned int*)l, 16, 0, 0);
}

// ---------------- fused fp32 -> bf16 convert for all 5 static tensors ----------------
#define Q0 524288    // hs        2048*1024 /4
#define Q1 1572864   // + W_in    4096*1024 /4
#define Q2 2097152   // + W_out   1024*2048 /4
#define Q3 2146304   // + W_x     96*2048   /4
#define Q4 2179072   // + W_dt    2048*64   /4
__global__ __launch_bounds__(256) void cvt_all(
    const float* __restrict__ i0, const float* __restrict__ i1,
    const float* __restrict__ i2, const float* __restrict__ i3,
    const float* __restrict__ i4,
    unsigned short* __restrict__ o0, unsigned short* __restrict__ o1,
    unsigned short* __restrict__ o2, unsigned short* __restrict__ o3,
    unsigned short* __restrict__ o4)
{
    int q = blockIdx.x * 256 + threadIdx.x;
    if (q >= Q4) return;
    const float* in; unsigned short* out; int base;
    if (q < Q0)      { in = i0; out = o0; base = 0; }
    else if (q < Q1) { in = i1; out = o1; base = Q0; }
    else if (q < Q2) { in = i2; out = o2; base = Q1; }
    else if (q < Q3) { in = i3; out = o3; base = Q2; }
    else             { in = i4; out = o4; base = Q3; }
    int i = (q - base) * 4;
    float4 v = *(const float4*)(in + i);
    ushort4 o;
    o.x = f2bf(v.x); o.y = f2bf(v.y); o.z = f2bf(v.z); o.w = f2bf(v.w);
    *(ushort4*)(out + i) = o;
}

// ---------------- fat-wave GEMM: C = A[M,K] @ B[N,K]^T, 128x128 tile, BK=64 -------
// 256 threads, 4 waves as 2x2, each wave 64x64 output (4x4 frags of 16x16x32).
// FLOP per LDS byte = 32. Double-buffered LDS (64 KB), depth-1 prefetch, counted
// vmcnt(8), raw s_barrier. Rule-21 swizzle: LDS linear, source col-slot and read
// col-slot both XOR (row&7) over the 8 16B slots. N multiple of 128, K mult of 64.
// XCD swizzle (T1): bijective remap (nwg must be divisible by 8) so each XCD's
// dispatch-round-robin share is a contiguous y-chunk -> A-panels stay L2-resident.
// EPI: 0 = split-K partial store C[z*partStride + m*ldc + n],
//      4 = proj: n<2048 -> C[m][n] (xpre); n>=2048 -> C2[m][n-2048] (gate)
template<int EPI>
__global__ __launch_bounds__(256) void gemm128(
    const unsigned short* __restrict__ A, const unsigned short* __restrict__ Bm,
    float* __restrict__ C, int K, int ldc, int kChunk,
    size_t partStride, float* __restrict__ C2)
{
    __shared__ unsigned short As[2][128 * 64];
    __shared__ unsigned short Bs[2][128 * 64];
    const int tid  = threadIdx.x;
    const int lane = tid & 63;
    const int wave = tid >> 6;
    const int wm = (wave >> 1) * 64;
    const int wn = (wave & 1) * 64;
    const int lr   = lane & 15;
    const int quad = lane >> 4;

    // XCD-aware bijective block swizzle (nwg % 8 == 0 for all call sites)
    const int nwg = gridDim.x * gridDim.y * gridDim.z;
    const int lin = blockIdx.x + gridDim.x * (blockIdx.y + gridDim.y * blockIdx.z);
    const int swz = (lin & 7) * (nwg >> 3) + (lin >> 3);
    const int bx  = swz % gridDim.x;
    const int tmp = swz / gridDim.x;
    const int by  = tmp % gridDim.y;
    const int bz  = tmp / gridDim.y;

    const int m0 = by * 128;
    const int n0 = bx * 128;
    const int k0 = bz * kChunk;

    // staging: per gl2lds call, wave w covers LDS rows w*8..w*8+7 (lane>>3 = row-in-8,
    // lane&7 = col slot). Source col-slot XOR'd by (row&7)=rowIn8 (rule 21).
    const int rowIn8 = lane >> 3;
    const int colSw  = ((lane & 7) ^ rowIn8) * 8;
    const int srow   = wave * 8 + rowIn8;               // 0..31
    const size_t aoff0 = (size_t)(m0 + srow +  0) * K + colSw;
    const size_t aoff1 = (size_t)(m0 + srow + 32) * K + colSw;
    const size_t aoff2 = (size_t)(m0 + srow + 64) * K + colSw;
    const size_t aoff3 = (size_t)(m0 + srow + 96) * K + colSw;
    const size_t boff0 = (size_t)(n0 + srow +  0) * K + colSw;
    const size_t boff1 = (size_t)(n0 + srow + 32) * K + colSw;
    const size_t boff2 = (size_t)(n0 + srow + 64) * K + colSw;
    const size_t boff3 = (size_t)(n0 + srow + 96) * K + colSw;
    // read slots: k-slice0 -> slot quad, k-slice1 -> slot 4+quad, both ^ (lr&7)
    const int rq0 = ((quad) ^ (lr & 7)) * 8;
    const int rq1 = rq0 ^ 32;

    floatx4 acc[4][4];
#pragma unroll
    for (int mi = 0; mi < 4; ++mi)
#pragma unroll
        for (int ni = 0; ni < 4; ++ni)
            acc[mi][ni] = (floatx4){0.f, 0.f, 0.f, 0.f};

#define STG(buf, kt)                                                    \
    do {                                                                \
        gl2lds(A + aoff0 + (kt), &As[buf][(0  + wave * 8) * 64]);       \
        gl2lds(A + aoff1 + (kt), &As[buf][(32 + wave * 8) * 64]);       \
        gl2lds(A + aoff2 + (kt), &As[buf][(64 + wave * 8) * 64]);       \
        gl2lds(A + aoff3 + (kt), &As[buf][(96 + wave * 8) * 64]);       \
        gl2lds(Bm + boff0 + (kt), &Bs[buf][(0  + wave * 8) * 64]);      \
        gl2lds(Bm + boff1 + (kt), &Bs[buf][(32 + wave * 8) * 64]);      \
        gl2lds(Bm + boff2 + (kt), &Bs[buf][(64 + wave * 8) * 64]);      \
        gl2lds(Bm + boff3 + (kt), &Bs[buf][(96 + wave * 8) * 64]);      \
    } while (0)

    STG(0, k0);

    const int nt = kChunk >> 6;
    for (int t = 0; t < nt; ++t) {
        const int cur = t & 1;
        if (t + 1 < nt) {
            STG(cur ^ 1, k0 + (t + 1) * 64);
            asm volatile("s_waitcnt vmcnt(8)" ::: "memory");  // tile t landed; t+1 in flight
        } else {
            asm volatile("s_waitcnt vmcnt(0)" ::: "memory");
        }
        __builtin_amdgcn_s_barrier();          // all waves see tile t in LDS
        __builtin_amdgcn_sched_barrier(0);     // pin: no LDS reads hoisted above

        short8 a0f[4], a1f[4], b0f[4], b1f[4];
#pragma unroll
        for (int mi = 0; mi < 4; ++mi) {
            a0f[mi] = *(const short8*)&As[cur][(wm + mi * 16 + lr) * 64 + rq0];
            a1f[mi] = *(const short8*)&As[cur][(wm + mi * 16 + lr) * 64 + rq1];
        }
#pragma unroll
        for (int ni = 0; ni < 4; ++ni) {
            b0f[ni] = *(const short8*)&Bs[cur][(wn + ni * 16 + lr) * 64 + rq0];
            b1f[ni] = *(const short8*)&Bs[cur][(wn + ni * 16 + lr) * 64 + rq1];
        }
#pragma unroll
        for (int mi = 0; mi < 4; ++mi)
#pragma unroll
            for (int ni = 0; ni < 4; ++ni)
                acc[mi][ni] = __builtin_amdgcn_mfma_f32_16x16x32_bf16(
                    a0f[mi], b0f[ni], acc[mi][ni], 0, 0, 0);
#pragma unroll
        for (int mi = 0; mi < 4; ++mi)
#pragma unroll
            for (int ni = 0; ni < 4; ++ni)
                acc[mi][ni] = __builtin_amdgcn_mfma_f32_16x16x32_bf16(
                    a1f[mi], b1f[ni], acc[mi][ni], 0, 0, 0);

        asm volatile("s_waitcnt lgkmcnt(0)" ::: "memory");  // this wave's reads retired
        __builtin_amdgcn_s_barrier();          // safe for next stage to overwrite cur
    }
#undef STG

    float* Cz = C + (size_t)bz * partStride;
#pragma unroll
    for (int mi = 0; mi < 4; ++mi)
#pragma unroll
        for (int ni = 0; ni < 4; ++ni) {
            const int rr = m0 + wm + mi * 16 + quad * 4;
            const int cc = n0 + wn + ni * 16 + lr;
            if (EPI == 4) {
                if (cc < 2048) {
#pragma unroll
                    for (int r = 0; r < 4; ++r)
                        C[(size_t)(rr + r) * 2048 + cc] = acc[mi][ni][r];
                } else {
#pragma unroll
                    for (int r = 0; r < 4; ++r)
                        C2[(size_t)(rr + r) * 2048 + (cc - 2048)] = acc[mi][ni][r];
                }
            } else {
#pragma unroll
                for (int r = 0; r < 4; ++r)
                    Cz[(size_t)(rr + r) * ldc + cc] = acc[mi][ni][r];
            }
        }
}

// ---------------- narrow GEMM (ssm): C = A[M,K] @ B[N,K]^T, 64x128 tile, BK=64 ----
// 4 waves as 2m x 2n, wave 32x64; counted vmcnt(6); row-clamped B (N=96).
__global__ __launch_bounds__(256) void gemm_ssm(
    const unsigned short* __restrict__ A, const unsigned short* __restrict__ Bm,
    float* __restrict__ C, int K, int Ncols, int ldc, int kChunk, int nMax,
    size_t partStride)
{
    __shared__ unsigned short As[2][64 * 64];
    __shared__ unsigned short Bs[2][128 * 64];
    const int tid  = threadIdx.x;
    const int lane = tid & 63;
    const int wave = tid >> 6;
    const int wm = (wave >> 1) * 32;
    const int wn = (wave & 1) * 64;
    const int lr   = lane & 15;
    const int quad = lane >> 4;
    const int m0 = blockIdx.y * 64;
    const int n0 = blockIdx.x * 128;
    const int k0 = blockIdx.z * kChunk;

    const int rowIn8 = lane >> 3;
    const int colSw  = ((lane & 7) ^ rowIn8) * 8;
    const size_t aoff0 = (size_t)(m0 + 0  + wave * 8 + rowIn8) * K + colSw;
    const size_t aoff1 = (size_t)(m0 + 32 + wave * 8 + rowIn8) * K + colSw;
    const size_t boff0 = (size_t)min(n0 + 0  + wave * 8 + rowIn8, nMax - 1) * K + colSw;
    const size_t boff1 = (size_t)min(n0 + 32 + wave * 8 + rowIn8, nMax - 1) * K + colSw;
    const size_t boff2 = (size_t)min(n0 + 64 + wave * 8 + rowIn8, nMax - 1) * K + colSw;
    const size_t boff3 = (size_t)min(n0 + 96 + wave * 8 + rowIn8, nMax - 1) * K + colSw;
    const int rq0 = ((quad) ^ (lr & 7)) * 8;
    const int rq1 = rq0 ^ 32;

    floatx4 acc[2][4];
#pragma unroll
    for (int mi = 0; mi < 2; ++mi)
#pragma unroll
        for (int ni = 0; ni < 4; ++ni)
            acc[mi][ni] = (floatx4){0.f, 0.f, 0.f, 0.f};

#define STAGE(buf, kt)                                                   \
    do {                                                                 \
        gl2lds(A + aoff0 + (kt), &As[buf][(0  + wave * 8) * 64]);        \
        gl2lds(A + aoff1 + (kt), &As[buf][(32 + wave * 8) * 64]);        \
        gl2lds(Bm + boff0 + (kt), &Bs[buf][(0   + wave * 8) * 64]);      \
        gl2lds(Bm + boff1 + (kt), &Bs[buf][(32  + wave * 8) * 64]);      \
        gl2lds(Bm + boff2 + (kt), &Bs[buf][(64  + wave * 8) * 64]);      \
        gl2lds(Bm + boff3 + (kt), &Bs[buf][(96  + wave * 8) * 64]);      \
    } while (0)

    STAGE(0, k0);

    const int nt = kChunk >> 6;
    for (int t = 0; t < nt; ++t) {
        const int cur = t & 1;
        if (t + 1 < nt) {
            STAGE(cur ^ 1, k0 + (t + 1) * 64);
            asm volatile("s_waitcnt vmcnt(6)" ::: "memory");
        } else {
            asm volatile("s_waitcnt vmcnt(0)" ::: "memory");
        }
        __builtin_amdgcn_s_barrier();
        __builtin_amdgcn_sched_barrier(0);

        short8 a0[2], a1[2], b0[4], b1[4];
#pragma unroll
        for (int mi = 0; mi < 2; ++mi) {
            a0[mi] = *(const short8*)&As[cur][(wm + mi * 16 + lr) * 64 + rq0];
            a1[mi] = *(const short8*)&As[cur][(wm + mi * 16 + lr) * 64 + rq1];
        }
#pragma unroll
        for (int ni = 0; ni < 4; ++ni) {
            b0[ni] = *(const short8*)&Bs[cur][(wn + ni * 16 + lr) * 64 + rq0];
            b1[ni] = *(const short8*)&Bs[cur][(wn + ni * 16 + lr) * 64 + rq1];
        }
#pragma unroll
        for (int mi = 0; mi < 2; ++mi)
#pragma unroll
            for (int ni = 0; ni < 4; ++ni)
                acc[mi][ni] = __builtin_amdgcn_mfma_f32_16x16x32_bf16(
                    a0[mi], b0[ni], acc[mi][ni], 0, 0, 0);
#pragma unroll
        for (int mi = 0; mi < 2; ++mi)
#pragma unroll
            for (int ni = 0; ni < 4; ++ni)
                acc[mi][ni] = __builtin_amdgcn_mfma_f32_16x16x32_bf16(
                    a1[mi], b1[ni], acc[mi][ni], 0, 0, 0);

        asm volatile("s_waitcnt lgkmcnt(0)" ::: "memory");
        __builtin_amdgcn_s_barrier();
    }
#undef STAGE

    float* Cz = C + (size_t)blockIdx.z * partStride;
#pragma unroll
    for (int mi = 0; mi < 2; ++mi)
#pragma unroll
        for (int ni = 0; ni < 4; ++ni) {
            const int rr = m0 + wm + mi * 16 + quad * 4;
            const int cc = n0 + wn + ni * 16 + lr;
            if (cc >= Ncols) continue;
#pragma unroll
            for (int r = 0; r < 4; ++r)
                Cz[(size_t)(rr + r) * ldc + cc] = acc[mi][ni][r];
        }
}

// ---------------- reduce 16 ssm partials -> ssm_p[m][96] + sp64_bf[m][64] ----------------
__global__ __launch_bounds__(256) void reduce_ssm(
    const float* __restrict__ P, float* __restrict__ ssm_p,
    unsigned short* __restrict__ sp64)
{
    const int q = blockIdx.x * 256 + threadIdx.x;    // 2048*24 quads
    const int m = q / 24;
    const int c = (q - m * 24) * 4;
    const size_t idx = (size_t)m * 96 + c;
    float4 s = make_float4(0.f, 0.f, 0.f, 0.f);
#pragma unroll
    for (int z = 0; z < 16; ++z) {
        float4 v = *(const float4*)(P + (size_t)z * (2048 * 96) + idx);
        s.x += v.x; s.y += v.y; s.z += v.z; s.w += v.w;
    }
    *(float4*)(ssm_p + idx) = s;
    if (c < 64) {
        ushort4 o;
        o.x = f2bf(s.x); o.y = f2bf(s.y); o.z = f2bf(s.z); o.w = f2bf(s.w);
        *(ushort4*)(sp64 + (size_t)m * 64 + c) = o;
    }
}

// ---------------- reduce 4 out partials -> out[m][h] ----------------
__global__ __launch_bounds__(256) void reduce_out(
    const float* __restrict__ P, float* __restrict__ out)
{
    const size_t i = ((size_t)blockIdx.x * 256 + threadIdx.x) * 4;  // 2048*1024 total
    float4 a = *(const float4*)(P + i);
    float4 b = *(const float4*)(P + 2097152 + i);
    float4 c = *(const float4*)(P + 2 * 2097152 + i);
    float4 d = *(const float4*)(P + 3 * 2097152 + i);
    *(float4*)(out + i) = make_float4(a.x + b.x + c.x + d.x,
                                      a.y + b.y + c.y + d.y,
                                      a.z + b.z + c.z + d.z,
                                      a.w + b.w + c.w + d.w);
}

// ---------------- dedicated dt GEMM: dt[m][d] = softplus(sp64 @ W_dt^T + b) -------
__global__ __launch_bounds__(256) void dt_gemm(
    const unsigned short* __restrict__ A,   // sp64_bf [2048 m][64]
    const unsigned short* __restrict__ Bm,  // W_dt_bf [2048 d][64]
    float* __restrict__ C,                  // dt [2048 m][2048 d]
    const float* __restrict__ bias)         // b_dt [2048]
{
    __shared__ unsigned short As[64 * 72];
    __shared__ unsigned short Bs[64 * 72];
    const int tid = threadIdx.x;
    const int lane = tid & 63;
    const int wave = tid >> 6;
    const int lr = lane & 15;
    const int quad = lane >> 4;
    const int n0 = blockIdx.x * 64;
    const int m0 = blockIdx.y * 64;

    {
        const int row = tid >> 3;
        const int cq = (tid & 7) * 8;
        uint4 a0 = *(const uint4*)(A + (size_t)(m0 + row) * 64 + cq);
        uint4 a1 = *(const uint4*)(A + (size_t)(m0 + 32 + row) * 64 + cq);
        uint4 b0 = *(const uint4*)(Bm + (size_t)(n0 + row) * 64 + cq);
        uint4 b1 = *(const uint4*)(Bm + (size_t)(n0 + 32 + row) * 64 + cq);
        *(uint4*)&As[row * 72 + cq] = a0;
        *(uint4*)&As[(32 + row) * 72 + cq] = a1;
        *(uint4*)&Bs[row * 72 + cq] = b0;
        *(uint4*)&Bs[(32 + row) * 72 + cq] = b1;
    }
    __syncthreads();

    floatx4 acc[4];
#pragma unroll
    for (int ni = 0; ni < 4; ++ni) acc[ni] = (floatx4){0.f, 0.f, 0.f, 0.f};

#pragma unroll
    for (int kt = 0; kt < 64; kt += 32) {
        short8 af = *(const short8*)&As[(wave * 16 + lr) * 72 + kt + quad * 8];
#pragma unroll
        for (int ni = 0; ni < 4; ++ni) {
            short8 bf = *(const short8*)&Bs[(ni * 16 + lr) * 72 + kt + quad * 8];
            acc[ni] = __builtin_amdgcn_mfma_f32_16x16x32_bf16(af, bf, acc[ni], 0, 0, 0);
        }
    }

    const int rr = m0 + wave * 16 + quad * 4;
#pragma unroll
    for (int ni = 0; ni < 4; ++ni) {
        const int cc = n0 + ni * 16 + lr;
        const float bv = bias[cc];
#pragma unroll
        for (int r = 0; r < 4; ++r) {
            const float z = acc[ni][r] + bv;
            const float spv = fmaxf(z, 0.f) + __logf(1.f + __expf(-fabsf(z)));
            C[(size_t)(rr + r) * 2048 + cc] = spv;
        }
    }
}

// ---------------- causal depthwise conv (K=4) + bias + SiLU, m-major f32 in ------
// xpre[m][d] staged through LDS: coalesced global reads, conflict-free LDS reads.
__global__ __launch_bounds__(256) void conv_silu_kernel(
    const float* __restrict__ xpre, const float* __restrict__ conv_w,
    const float* __restrict__ conv_b, unsigned short* __restrict__ x_bf)
{
    __shared__ float inT[67][64];            // rows r <-> l = lt0 + r - 3
    __shared__ unsigned short tile[64][72];  // out staging for coalesced store
    const int t = threadIdx.x;
    const int d0 = blockIdx.x * 64;
    const int lt0 = blockIdx.y * 64;
    const int b = blockIdx.z;

    {
        const int r = t >> 2;          // 0..63
        const int q = (t & 3) * 16;    // 0,16,32,48
        const int l = lt0 + r - 3;
        if (l >= 0) {
            const float* src = xpre + ((size_t)(b * 1024 + l)) * 2048 + d0 + q;
            *(float4*)&inT[r][q + 0]  = *(const float4*)(src + 0);
            *(float4*)&inT[r][q + 4]  = *(const float4*)(src + 4);
            *(float4*)&inT[r][q + 8]  = *(const float4*)(src + 8);
            *(float4*)&inT[r][q + 12] = *(const float4*)(src + 12);
        } else {
            float4 z4 = make_float4(0.f, 0.f, 0.f, 0.f);
            *(float4*)&inT[r][q + 0]  = z4;
            *(float4*)&inT[r][q + 4]  = z4;
            *(float4*)&inT[r][q + 8]  = z4;
            *(float4*)&inT[r][q + 12] = z4;
        }
        if (t < 12) {
            const int r2 = 64 + (t >> 2);      // 64..66
            const int l2 = lt0 + r2 - 3;       // = lt0 + 61..63, always >= 0
            const float* src = xpre + ((size_t)(b * 1024 + l2)) * 2048 + d0 + q;
            *(float4*)&inT[r2][q + 0]  = *(const float4*)(src + 0);
            *(float4*)&inT[r2][q + 4]  = *(const float4*)(src + 4);
            *(float4*)&inT[r2][q + 8]  = *(const float4*)(src + 8);
            *(float4*)&inT[r2][q + 12] = *(const float4*)(src + 12);
        }
    }
    __syncthreads();

    const int dl = t & 63;
    const int seg = t >> 6;
    const int d = d0 + dl;
    const float w0 = conv_w[d * 4 + 0], w1 = conv_w[d * 4 + 1];
    const float w2 = conv_w[d * 4 + 2], w3 = conv_w[d * 4 + 3];
    const float bias = conv_b[d];

    float p[19];
#pragma unroll
    for (int j = 0; j < 19; ++j) p[j] = inT[seg * 16 + j][dl];
#pragma unroll
    for (int j = 0; j < 16; ++j) {
        float v = siluf(bias + w0 * p[j] + w1 * p[j + 1] + w2 * p[j + 2] + w3 * p[j + 3]);
        tile[seg * 16 + j][dl] = f2bf(v);
    }
    __syncthreads();

    const int ml = t >> 2;
    const int c = t & 3;
    short8 s0 = *(const short8*)&tile[ml][c * 16];
    short8 s1 = *(const short8*)&tile[ml][c * 16 + 8];
    unsigned short* dst = x_bf + (size_t)(b * 1024 + lt0 + ml) * 2048 + d0 + c * 16;
    *(short8*)dst = s0;
    *(short8*)(dst + 8) = s1;
}

// ---------------- scan pass 1: per-chunk H[n] (from h=0) + dt-sum scalar ----------------
__global__ __launch_bounds__(256) void scan_p1(
    const float* __restrict__ dt, const unsigned short* __restrict__ x_bf,
    const float* __restrict__ sp, const float* __restrict__ A_log,
    float* __restrict__ Dts, float* __restrict__ Hch)
{
    __shared__ float sB[CL][16];
    const int tid = threadIdx.x;
    const int d = blockIdx.x * 256 + tid;
    const int ck = blockIdx.y;
    const int b = blockIdx.z;
    const int mb = b * 1024 + ck * CL;

    if (tid < CL * 4) {
        int row = tid >> 2, q = (tid & 3) * 4;
        *(float4*)&sB[row][q] = *(const float4*)(sp + (size_t)(mb + row) * 96 + 64 + q);
    }
    float An2[16];
    {
        const float* al = A_log + d * 16;
#pragma unroll
        for (int j = 0; j < 16; j += 4) {
            float4 a4 = *(const float4*)(al + j);
            An2[j + 0] = -__expf(a4.x) * 1.44269504f;
            An2[j + 1] = -__expf(a4.y) * 1.44269504f;
            An2[j + 2] = -__expf(a4.z) * 1.44269504f;
            An2[j + 3] = -__expf(a4.w) * 1.44269504f;
        }
    }
    __syncthreads();

    float h[16];
#pragma unroll
    for (int n = 0; n < 16; ++n) h[n] = 0.f;
    float dts = 0.f;

    for (int l = 0; l < CL; ++l) {
        const size_t off = (size_t)(mb + l) * 2048 + d;
        const float dtv = dt[off];
        const float xv = bf2f(x_bf[off]);
        const float u = dtv * xv;
        dts += dtv;
        float4 B0 = *(const float4*)&sB[l][0];
        float4 B1 = *(const float4*)&sB[l][4];
        float4 B2 = *(const float4*)&sB[l][8];
        float4 B3 = *(const float4*)&sB[l][12];
        float Bv[16] = {B0.x, B0.y, B0.z, B0.w, B1.x, B1.y, B1.z, B1.w,
                        B2.x, B2.y, B2.z, B2.w, B3.x, B3.y, B3.z, B3.w};
#pragma unroll
        for (int n = 0; n < 16; ++n) {
            const float dA = __builtin_amdgcn_exp2f(dtv * An2[n]);
            h[n] = fmaf(dA, h[n], Bv[n] * u);
        }
    }

    const size_t cb = (size_t)(b * NCK + ck) * 2048 + d;
    Dts[cb] = dts;
    const size_t base = cb * 16;
#pragma unroll
    for (int j = 0; j < 16; j += 4)
        *(float4*)(Hch + base + j) = make_float4(h[j], h[j + 1], h[j + 2], h[j + 3]);
}

// ---------------- scan combine: serial over chunks; recompute P from dts ------
__global__ __launch_bounds__(256) void scan_combine(
    const float* __restrict__ Dts, const float* __restrict__ Hch,
    const float* __restrict__ A_log, float* __restrict__ Hin)
{
    const int flat = blockIdx.x * 256 + threadIdx.x;   // 2*2048*16
    const int dn = flat & 32767;
    const int b = flat >> 15;
    const int d = dn >> 4;
    const float An2 = -__expf(A_log[dn]) * 1.44269504f;
    float hin = 0.f;
#pragma unroll 4
    for (int ck = 0; ck < NCK; ++ck) {
        const size_t cb = (size_t)(b * NCK + ck) * 2048 + d;
        const float p = __builtin_amdgcn_exp2f(Dts[cb] * An2);
        const size_t a = ((size_t)(b * NCK + ck) << 15) + dn;
        const float hc = Hch[a];
        Hin[a] = hin;
        hin = fmaf(p, hin, hc);
    }
}

// ---------------- scan pass 2: rescan with h_in + fused gating -> y_bf[m][d] ----
__global__ __launch_bounds__(256) void scan_p2(
    const float* __restrict__ dt, const unsigned short* __restrict__ x_bf,
    const float* __restrict__ gate, const float* __restrict__ sp,
    const float* __restrict__ A_log, const float* __restrict__ Dp,
    const float* __restrict__ Hin, unsigned short* __restrict__ y_bf)
{
    __shared__ float sBC[CL][32];
    const int tid = threadIdx.x;
    const int d = blockIdx.x * 256 + tid;
    const int ck = blockIdx.y;
    const int b = blockIdx.z;
    const int mb = b * 1024 + ck * CL;

    {
        int row = tid >> 3, q = (tid & 7) * 4;
        *(float4*)&sBC[row][q] = *(const float4*)(sp + (size_t)(mb + row) * 96 + 64 + q);
    }
    float An2[16];
    {
        const float* al = A_log + d * 16;
#pragma unroll
        for (int j = 0; j < 16; j += 4) {
            float4 a4 = *(const float4*)(al + j);
            An2[j + 0] = -__expf(a4.x) * 1.44269504f;
            An2[j + 1] = -__expf(a4.y) * 1.44269504f;
            An2[j + 2] = -__expf(a4.z) * 1.44269504f;
            An2[j + 3] = -__expf(a4.w) * 1.44269504f;
        }
    }
    float h[16];
    {
        const size_t base = ((size_t)(b * NCK + ck) * 2048 + d) * 16;
#pragma unroll
        for (int j = 0; j < 16; j += 4) {
            float4 hv = *(const float4*)(Hin + base + j);
            h[j] = hv.x; h[j + 1] = hv.y; h[j + 2] = hv.z; h[j + 3] = hv.w;
        }
    }
    const float Dv = Dp[d];
    __syncthreads();

    for (int l = 0; l < CL; ++l) {
        const size_t off = (size_t)(mb + l) * 2048 + d;
        const float dtv = dt[off];
        const float xv = bf2f(x_bf[off]);
        const float gv = gate[off];
        const float u = dtv * xv;
        float4 B0 = *(const float4*)&sBC[l][0];
        float4 B1 = *(const float4*)&sBC[l][4];
        float4 B2 = *(const float4*)&sBC[l][8];
        float4 B3 = *(const float4*)&sBC[l][12];
        float Bv[16] = {B0.x, B0.y, B0.z, B0.w, B1.x, B1.y, B1.z, B1.w,
                        B2.x, B2.y, B2.z, B2.w, B3.x, B3.y, B3.z, B3.w};
#pragma unroll
        for (int n = 0; n < 16; ++n) {
            const float dA = __builtin_amdgcn_exp2f(dtv * An2[n]);
            h[n] = fmaf(dA, h[n], Bv[n] * u);
        }
        float4 C0 = *(const float4*)&sBC[l][16];
        float4 C1 = *(const float4*)&sBC[l][20];
        float4 C2 = *(const float4*)&sBC[l][24];
        float4 C3 = *(const float4*)&sBC[l][28];
        float Cv[16] = {C0.x, C0.y, C0.z, C0.w, C1.x, C1.y, C1.z, C1.w,
                        C2.x, C2.y, C2.z, C2.w, C3.x, C3.y, C3.z, C3.w};
        float p = 0.f;
#pragma unroll
        for (int n = 0; n < 16; ++n)
            p = fmaf(h[n], Cv[n], p);
        y_bf[off] = f2bf(fmaf(xv, Dv, p) * siluf(gv));
    }
}

extern "C" void kernel_launch(void* const* d_in, const int* in_sizes, int n_in,
                              void* d_out, int out_size, void* d_ws, size_t ws_size,
                              hipStream_t stream)
{
    const float* hs     = (const float*)d_in[0];
    const float* W_in   = (const float*)d_in[1];
    const float* conv_w = (const float*)d_in[2];
    const float* conv_b = (const float*)d_in[3];
    const float* W_x    = (const float*)d_in[4];
    const float* W_dt   = (const float*)d_in[5];
    const float* b_dt   = (const float*)d_in[6];
    const float* A_log  = (const float*)d_in[7];
    const float* Dp     = (const float*)d_in[8];
    const float* W_out  = (const float*)d_in[9];
    float* out = (float*)d_out;

    // workspace (~78 MB live) with overlays
    float* ws    = (float*)d_ws;
    float* gate  = ws;                               // [2048 m][2048 d] f32
    float* dtb   = gate + (size_t)4194304;           // [2048 m][2048 d] f32
    float* xpre  = dtb + (size_t)4194304;            // [2048 m][2048 d] f32 (dead after conv)
    float* ssm_p = xpre + (size_t)4194304;           // [2048 m][96] f32
    unsigned short* hs_bf    = (unsigned short*)(ssm_p + 196608);   // 2048*1024
    unsigned short* W_in_bf  = hs_bf + (size_t)2097152;             // 4096*1024
    unsigned short* W_out_bf = W_in_bf + (size_t)4194304;           // 1024*2048
    unsigned short* W_x_bf   = W_out_bf + (size_t)2097152;          // 96*2048
    unsigned short* W_dt_bf  = W_x_bf + (size_t)196608;             // 2048*64
    unsigned short* sp64_bf  = W_dt_bf + (size_t)131072;            // 2048*64
    unsigned short* x_bf     = sp64_bf + (size_t)131072;            // [2048 m][2048 d]
    float* Dts  = (float*)(x_bf + (size_t)4194304);   // [2*32][2048] dt-sums (0.5 MB)
    float* P1   = xpre;                               // overlay: ssm partials 16*2048*96
    float* Hin  = xpre;                               // overlay after reduce_ssm: 2*32*2048*16
    float* Hch  = xpre + (size_t)2097152;             // overlay
    float* Pout = gate;                               // overlay after scan_p2: 4*2048*1024 (gate+dtb, both dead)
    unsigned short* y_bf = hs_bf;                     // overlay (hs_bf+W_in_bf dead)

    const int M = B_ * L_;  // 2048

    // 0. fused fp32 -> bf16 converts (hs, W_in, W_out, W_x, W_dt)
    cvt_all<<<(Q4 + 255) / 256, 256, 0, stream>>>(
        hs, W_in, W_out, W_x, W_dt, hs_bf, W_in_bf, W_out_bf, W_x_bf, W_dt_bf);

    // 1. proj GEMM: 128x128 fat-wave tile, BK=64 -> 512 blocks (XCD-swizzled), nt=16
    gemm128<4><<<dim3(4096 / 128, M / 128, 1), 256, 0, stream>>>(
        hs_bf, W_in_bf, xpre, 1024, 2048, 1024, 0, gate);

    // 2. conv + SiLU (m-major in via LDS stage) -> x_bf[m][d]
    conv_silu_kernel<<<dim3(D_ / 64, L_ / 64, B_), 256, 0, stream>>>(
        xpre, conv_w, conv_b, x_bf);

    // 3. ssm partials: P1[z][m][96] = x @ W_x^T (K-chunk 128, 16 splits, nt=2)
    gemm_ssm<<<dim3(1, M / 64, 16), 256, 0, stream>>>(
        x_bf, W_x_bf, P1, 2048, 96, 96, 128, 96, (size_t)2048 * 96);

    // 3b. reduce 16 partials -> ssm_p[m][96] + sp64_bf[m][64]
    reduce_ssm<<<(2048 * 24) / 256, 256, 0, stream>>>(P1, ssm_p, sp64_bf);

    // 4. dt[m][d] = softplus(dt_lr @ W_dt^T + b_dt[d]) — dedicated 64x64 kernel
    dt_gemm<<<dim3(2048 / 64, 2048 / 64), 256, 0, stream>>>(
        sp64_bf, W_dt_bf, dtb, b_dt);

    // 5. scan: pass1 -> combine (P recomputed from dts) -> pass2 (writes y_bf[m][d])
    scan_p1<<<dim3(D_ / 256, NCK, B_), 256, 0, stream>>>(
        dtb, x_bf, ssm_p, A_log, Dts, Hch);
    scan_combine<<<(B_ * D_ * 16) / 256, 256, 0, stream>>>(Dts, Hch, A_log, Hin);
    scan_p2<<<dim3(D_ / 256, NCK, B_), 256, 0, stream>>>(
        dtb, x_bf, gate, ssm_p, A_log, Dp, Hin, y_bf);

    // 6. out partials: 128x128 fat-wave, K-chunk 512, 4 splits -> 512 blocks (swizzled)
    gemm128<0><<<dim3(1024 / 128, M / 128, 4), 256, 0, stream>>>(
        y_bf, W_out_bf, Pout, 2048, 1024, 512, (size_t)2048 * 1024, nullptr);

    // 6b. reduce 4 partials -> out
    reduce_out<<<(2048 * 1024 / 4) / 256, 256, 0, stream>>>(Pout, out);
}

// Round 11
// 211.535 us; speedup vs baseline: 1.0627x; 1.0400x over previous
//
#include <hip/hip_runtime.h>
#include <hip/hip_bf16.h>
#include <math.h>

#define B_ 2
#define L_ 1024
#define H_ 1024
#define D_ 2048
#define N_ 16
#define R_ 64
#define NCK 32     // chunks per sequence
#define CL 32      // chunk length (NCK*CL == L_)

typedef short short8 __attribute__((ext_vector_type(8)));
typedef float floatx4 __attribute__((ext_vector_type(4)));

__device__ __forceinline__ float siluf(float g) {
    return g / (1.0f + __expf(-g));
}

__device__ __forceinline__ unsigned short f2bf(float f) {
    unsigned int u = __float_as_uint(f);
    u = (u + 0x7fffu + ((u >> 16) & 1u)) >> 16;  // RNE
    return (unsigned short)u;
}

__device__ __forceinline__ float bf2f(unsigned short u) {
    return __uint_as_float(((unsigned int)u) << 16);
}

// async global->LDS, 16B per lane; lds base must be wave-uniform
__device__ __forceinline__ void gl2lds(const unsigned short* g, unsigned short* l) {
    __builtin_amdgcn_global_load_lds(
        (const __attribute__((address_space(1))) unsigned int*)g,
        (__attribute__((address_space(3))) unsigned int*)l, 16, 0, 0);
}

// ---------------- fused fp32 -> bf16 convert for all 5 static tensors ----------------
#define Q0 524288    // hs        2048*1024 /4
#define Q1 1572864   // + W_in    4096*1024 /4
#define Q2 2097152   // + W_out   1024*2048 /4
#define Q3 2146304   // + W_x     96*2048   /4
#define Q4 2179072   // + W_dt    2048*64   /4
__global__ __launch_bounds__(256) void cvt_all(
    const float* __restrict__ i0, const float* __restrict__ i1,
    const float* __restrict__ i2, const float* __restrict__ i3,
    const float* __restrict__ i4,
    unsigned short* __restrict__ o0, unsigned short* __restrict__ o1,
    unsigned short* __restrict__ o2, unsigned short* __restrict__ o3,
    unsigned short* __restrict__ o4)
{
    int q = blockIdx.x * 256 + threadIdx.x;
    if (q >= Q4) return;
    const float* in; unsigned short* out; int base;
    if (q < Q0)      { in = i0; out = o0; base = 0; }
    else if (q < Q1) { in = i1; out = o1; base = Q0; }
    else if (q < Q2) { in = i2; out = o2; base = Q1; }
    else if (q < Q3) { in = i3; out = o3; base = Q2; }
    else             { in = i4; out = o4; base = Q3; }
    int i = (q - base) * 4;
    float4 v = *(const float4*)(in + i);
    ushort4 o;
    o.x = f2bf(v.x); o.y = f2bf(v.y); o.z = f2bf(v.z); o.w = f2bf(v.w);
    *(ushort4*)(out + i) = o;
}

// ---------------- fat-wave GEMM: C = A[M,K] @ B[N,K]^T, 128x128 tile, BK=64 -------
// 256 threads, 4 waves as 2x2, each wave 64x64 output (4x4 frags of 16x16x32).
// FLOP per LDS byte = 32. Double-buffered LDS (64 KB), depth-1 prefetch, counted
// vmcnt(8), raw s_barrier. Rule-21 swizzle: LDS linear, source col-slot and read
// col-slot both XOR (row&7) over the 8 16B slots. N multiple of 128, K mult of 64.
// XCD swizzle (T1): bijective remap (nwg must be divisible by 8).
// EPI: 0 = split-K partial store C[z*partStride + m*ldc + n],
//      4 = proj: n<2048 -> C[m][n] (xpre); n>=2048 -> C2[m][n-2048] (gate)
template<int EPI>
__global__ __launch_bounds__(256) void gemm128(
    const unsigned short* __restrict__ A, const unsigned short* __restrict__ Bm,
    float* __restrict__ C, int K, int ldc, int kChunk,
    size_t partStride, float* __restrict__ C2)
{
    __shared__ unsigned short As[2][128 * 64];
    __shared__ unsigned short Bs[2][128 * 64];
    const int tid  = threadIdx.x;
    const int lane = tid & 63;
    const int wave = tid >> 6;
    const int wm = (wave >> 1) * 64;
    const int wn = (wave & 1) * 64;
    const int lr   = lane & 15;
    const int quad = lane >> 4;

    // XCD-aware bijective block swizzle (nwg % 8 == 0 for all call sites)
    const int nwg = gridDim.x * gridDim.y * gridDim.z;
    const int lin = blockIdx.x + gridDim.x * (blockIdx.y + gridDim.y * blockIdx.z);
    const int swz = (lin & 7) * (nwg >> 3) + (lin >> 3);
    const int bx  = swz % gridDim.x;
    const int tmp = swz / gridDim.x;
    const int by  = tmp % gridDim.y;
    const int bz  = tmp / gridDim.y;

    const int m0 = by * 128;
    const int n0 = bx * 128;
    const int k0 = bz * kChunk;

    const int rowIn8 = lane >> 3;
    const int colSw  = ((lane & 7) ^ rowIn8) * 8;
    const int srow   = wave * 8 + rowIn8;               // 0..31
    const size_t aoff0 = (size_t)(m0 + srow +  0) * K + colSw;
    const size_t aoff1 = (size_t)(m0 + srow + 32) * K + colSw;
    const size_t aoff2 = (size_t)(m0 + srow + 64) * K + colSw;
    const size_t aoff3 = (size_t)(m0 + srow + 96) * K + colSw;
    const size_t boff0 = (size_t)(n0 + srow +  0) * K + colSw;
    const size_t boff1 = (size_t)(n0 + srow + 32) * K + colSw;
    const size_t boff2 = (size_t)(n0 + srow + 64) * K + colSw;
    const size_t boff3 = (size_t)(n0 + srow + 96) * K + colSw;
    const int rq0 = ((quad) ^ (lr & 7)) * 8;
    const int rq1 = rq0 ^ 32;

    floatx4 acc[4][4];
#pragma unroll
    for (int mi = 0; mi < 4; ++mi)
#pragma unroll
        for (int ni = 0; ni < 4; ++ni)
            acc[mi][ni] = (floatx4){0.f, 0.f, 0.f, 0.f};

#define STG(buf, kt)                                                    \
    do {                                                                \
        gl2lds(A + aoff0 + (kt), &As[buf][(0  + wave * 8) * 64]);       \
        gl2lds(A + aoff1 + (kt), &As[buf][(32 + wave * 8) * 64]);       \
        gl2lds(A + aoff2 + (kt), &As[buf][(64 + wave * 8) * 64]);       \
        gl2lds(A + aoff3 + (kt), &As[buf][(96 + wave * 8) * 64]);       \
        gl2lds(Bm + boff0 + (kt), &Bs[buf][(0  + wave * 8) * 64]);      \
        gl2lds(Bm + boff1 + (kt), &Bs[buf][(32 + wave * 8) * 64]);      \
        gl2lds(Bm + boff2 + (kt), &Bs[buf][(64 + wave * 8) * 64]);      \
        gl2lds(Bm + boff3 + (kt), &Bs[buf][(96 + wave * 8) * 64]);      \
    } while (0)

    STG(0, k0);

    const int nt = kChunk >> 6;
    for (int t = 0; t < nt; ++t) {
        const int cur = t & 1;
        if (t + 1 < nt) {
            STG(cur ^ 1, k0 + (t + 1) * 64);
            asm volatile("s_waitcnt vmcnt(8)" ::: "memory");  // tile t landed; t+1 in flight
        } else {
            asm volatile("s_waitcnt vmcnt(0)" ::: "memory");
        }
        __builtin_amdgcn_s_barrier();          // all waves see tile t in LDS
        __builtin_amdgcn_sched_barrier(0);     // pin: no LDS reads hoisted above

        short8 a0f[4], a1f[4], b0f[4], b1f[4];
#pragma unroll
        for (int mi = 0; mi < 4; ++mi) {
            a0f[mi] = *(const short8*)&As[cur][(wm + mi * 16 + lr) * 64 + rq0];
            a1f[mi] = *(const short8*)&As[cur][(wm + mi * 16 + lr) * 64 + rq1];
        }
#pragma unroll
        for (int ni = 0; ni < 4; ++ni) {
            b0f[ni] = *(const short8*)&Bs[cur][(wn + ni * 16 + lr) * 64 + rq0];
            b1f[ni] = *(const short8*)&Bs[cur][(wn + ni * 16 + lr) * 64 + rq1];
        }
#pragma unroll
        for (int mi = 0; mi < 4; ++mi)
#pragma unroll
            for (int ni = 0; ni < 4; ++ni)
                acc[mi][ni] = __builtin_amdgcn_mfma_f32_16x16x32_bf16(
                    a0f[mi], b0f[ni], acc[mi][ni], 0, 0, 0);
#pragma unroll
        for (int mi = 0; mi < 4; ++mi)
#pragma unroll
            for (int ni = 0; ni < 4; ++ni)
                acc[mi][ni] = __builtin_amdgcn_mfma_f32_16x16x32_bf16(
                    a1f[mi], b1f[ni], acc[mi][ni], 0, 0, 0);

        asm volatile("s_waitcnt lgkmcnt(0)" ::: "memory");  // this wave's reads retired
        __builtin_amdgcn_s_barrier();          // safe for next stage to overwrite cur
    }
#undef STG

    float* Cz = C + (size_t)bz * partStride;
#pragma unroll
    for (int mi = 0; mi < 4; ++mi)
#pragma unroll
        for (int ni = 0; ni < 4; ++ni) {
            const int rr = m0 + wm + mi * 16 + quad * 4;
            const int cc = n0 + wn + ni * 16 + lr;
            if (EPI == 4) {
                if (cc < 2048) {
#pragma unroll
                    for (int r = 0; r < 4; ++r)
                        C[(size_t)(rr + r) * 2048 + cc] = acc[mi][ni][r];
                } else {
#pragma unroll
                    for (int r = 0; r < 4; ++r)
                        C2[(size_t)(rr + r) * 2048 + (cc - 2048)] = acc[mi][ni][r];
                }
            } else {
#pragma unroll
                for (int r = 0; r < 4; ++r)
                    Cz[(size_t)(rr + r) * ldc + cc] = acc[mi][ni][r];
            }
        }
}

// ---------------- narrow GEMM (ssm): C = A[M,K] @ B[N,K]^T, 64x128 tile, BK=64 ----
// 4 waves as 2m x 2n, wave 32x64; counted vmcnt(6); row-clamped B (N=96).
__global__ __launch_bounds__(256) void gemm_ssm(
    const unsigned short* __restrict__ A, const unsigned short* __restrict__ Bm,
    float* __restrict__ C, int K, int Ncols, int ldc, int kChunk, int nMax,
    size_t partStride)
{
    __shared__ unsigned short As[2][64 * 64];
    __shared__ unsigned short Bs[2][128 * 64];
    const int tid  = threadIdx.x;
    const int lane = tid & 63;
    const int wave = tid >> 6;
    const int wm = (wave >> 1) * 32;
    const int wn = (wave & 1) * 64;
    const int lr   = lane & 15;
    const int quad = lane >> 4;
    const int m0 = blockIdx.y * 64;
    const int n0 = blockIdx.x * 128;
    const int k0 = blockIdx.z * kChunk;

    const int rowIn8 = lane >> 3;
    const int colSw  = ((lane & 7) ^ rowIn8) * 8;
    const size_t aoff0 = (size_t)(m0 + 0  + wave * 8 + rowIn8) * K + colSw;
    const size_t aoff1 = (size_t)(m0 + 32 + wave * 8 + rowIn8) * K + colSw;
    const size_t boff0 = (size_t)min(n0 + 0  + wave * 8 + rowIn8, nMax - 1) * K + colSw;
    const size_t boff1 = (size_t)min(n0 + 32 + wave * 8 + rowIn8, nMax - 1) * K + colSw;
    const size_t boff2 = (size_t)min(n0 + 64 + wave * 8 + rowIn8, nMax - 1) * K + colSw;
    const size_t boff3 = (size_t)min(n0 + 96 + wave * 8 + rowIn8, nMax - 1) * K + colSw;
    const int rq0 = ((quad) ^ (lr & 7)) * 8;
    const int rq1 = rq0 ^ 32;

    floatx4 acc[2][4];
#pragma unroll
    for (int mi = 0; mi < 2; ++mi)
#pragma unroll
        for (int ni = 0; ni < 4; ++ni)
            acc[mi][ni] = (floatx4){0.f, 0.f, 0.f, 0.f};

#define STAGE(buf, kt)                                                   \
    do {                                                                 \
        gl2lds(A + aoff0 + (kt), &As[buf][(0  + wave * 8) * 64]);        \
        gl2lds(A + aoff1 + (kt), &As[buf][(32 + wave * 8) * 64]);        \
        gl2lds(Bm + boff0 + (kt), &Bs[buf][(0   + wave * 8) * 64]);      \
        gl2lds(Bm + boff1 + (kt), &Bs[buf][(32  + wave * 8) * 64]);      \
        gl2lds(Bm + boff2 + (kt), &Bs[buf][(64  + wave * 8) * 64]);      \
        gl2lds(Bm + boff3 + (kt), &Bs[buf][(96  + wave * 8) * 64]);      \
    } while (0)

    STAGE(0, k0);

    const int nt = kChunk >> 6;
    for (int t = 0; t < nt; ++t) {
        const int cur = t & 1;
        if (t + 1 < nt) {
            STAGE(cur ^ 1, k0 + (t + 1) * 64);
            asm volatile("s_waitcnt vmcnt(6)" ::: "memory");
        } else {
            asm volatile("s_waitcnt vmcnt(0)" ::: "memory");
        }
        __builtin_amdgcn_s_barrier();
        __builtin_amdgcn_sched_barrier(0);

        short8 a0[2], a1[2], b0[4], b1[4];
#pragma unroll
        for (int mi = 0; mi < 2; ++mi) {
            a0[mi] = *(const short8*)&As[cur][(wm + mi * 16 + lr) * 64 + rq0];
            a1[mi] = *(const short8*)&As[cur][(wm + mi * 16 + lr) * 64 + rq1];
        }
#pragma unroll
        for (int ni = 0; ni < 4; ++ni) {
            b0[ni] = *(const short8*)&Bs[cur][(wn + ni * 16 + lr) * 64 + rq0];
            b1[ni] = *(const short8*)&Bs[cur][(wn + ni * 16 + lr) * 64 + rq1];
        }
#pragma unroll
        for (int mi = 0; mi < 2; ++mi)
#pragma unroll
            for (int ni = 0; ni < 4; ++ni)
                acc[mi][ni] = __builtin_amdgcn_mfma_f32_16x16x32_bf16(
                    a0[mi], b0[ni], acc[mi][ni], 0, 0, 0);
#pragma unroll
        for (int mi = 0; mi < 2; ++mi)
#pragma unroll
            for (int ni = 0; ni < 4; ++ni)
                acc[mi][ni] = __builtin_amdgcn_mfma_f32_16x16x32_bf16(
                    a1[mi], b1[ni], acc[mi][ni], 0, 0, 0);

        asm volatile("s_waitcnt lgkmcnt(0)" ::: "memory");
        __builtin_amdgcn_s_barrier();
    }
#undef STAGE

    float* Cz = C + (size_t)blockIdx.z * partStride;
#pragma unroll
    for (int mi = 0; mi < 2; ++mi)
#pragma unroll
        for (int ni = 0; ni < 4; ++ni) {
            const int rr = m0 + wm + mi * 16 + quad * 4;
            const int cc = n0 + wn + ni * 16 + lr;
            if (cc >= Ncols) continue;
#pragma unroll
            for (int r = 0; r < 4; ++r)
                Cz[(size_t)(rr + r) * ldc + cc] = acc[mi][ni][r];
        }
}

// ---------------- reduce 16 ssm partials -> ssm_p[m][96] + sp64_bf[m][64] ----------------
__global__ __launch_bounds__(256) void reduce_ssm(
    const float* __restrict__ P, float* __restrict__ ssm_p,
    unsigned short* __restrict__ sp64)
{
    const int q = blockIdx.x * 256 + threadIdx.x;    // 2048*24 quads
    const int m = q / 24;
    const int c = (q - m * 24) * 4;
    const size_t idx = (size_t)m * 96 + c;
    float4 s = make_float4(0.f, 0.f, 0.f, 0.f);
#pragma unroll
    for (int z = 0; z < 16; ++z) {
        float4 v = *(const float4*)(P + (size_t)z * (2048 * 96) + idx);
        s.x += v.x; s.y += v.y; s.z += v.z; s.w += v.w;
    }
    *(float4*)(ssm_p + idx) = s;
    if (c < 64) {
        ushort4 o;
        o.x = f2bf(s.x); o.y = f2bf(s.y); o.z = f2bf(s.z); o.w = f2bf(s.w);
        *(ushort4*)(sp64 + (size_t)m * 64 + c) = o;
    }
}

// ---------------- reduce 4 out partials -> out[m][h] ----------------
__global__ __launch_bounds__(256) void reduce_out(
    const float* __restrict__ P, float* __restrict__ out)
{
    const size_t i = ((size_t)blockIdx.x * 256 + threadIdx.x) * 4;  // 2048*1024 total
    float4 a = *(const float4*)(P + i);
    float4 b = *(const float4*)(P + 2097152 + i);
    float4 c = *(const float4*)(P + 2 * 2097152 + i);
    float4 d = *(const float4*)(P + 3 * 2097152 + i);
    *(float4*)(out + i) = make_float4(a.x + b.x + c.x + d.x,
                                      a.y + b.y + c.y + d.y,
                                      a.z + b.z + c.z + d.z,
                                      a.w + b.w + c.w + d.w);
}

// ---------------- causal depthwise conv (K=4) + bias + SiLU, m-major f32 in ------
// xpre[m][d] staged through LDS: coalesced global reads, conflict-free LDS reads.
__global__ __launch_bounds__(256) void conv_silu_kernel(
    const float* __restrict__ xpre, const float* __restrict__ conv_w,
    const float* __restrict__ conv_b, unsigned short* __restrict__ x_bf)
{
    __shared__ float inT[67][64];            // rows r <-> l = lt0 + r - 3
    __shared__ unsigned short tile[64][72];  // out staging for coalesced store
    const int t = threadIdx.x;
    const int d0 = blockIdx.x * 64;
    const int lt0 = blockIdx.y * 64;
    const int b = blockIdx.z;

    {
        const int r = t >> 2;          // 0..63
        const int q = (t & 3) * 16;    // 0,16,32,48
        const int l = lt0 + r - 3;
        if (l >= 0) {
            const float* src = xpre + ((size_t)(b * 1024 + l)) * 2048 + d0 + q;
            *(float4*)&inT[r][q + 0]  = *(const float4*)(src + 0);
            *(float4*)&inT[r][q + 4]  = *(const float4*)(src + 4);
            *(float4*)&inT[r][q + 8]  = *(const float4*)(src + 8);
            *(float4*)&inT[r][q + 12] = *(const float4*)(src + 12);
        } else {
            float4 z4 = make_float4(0.f, 0.f, 0.f, 0.f);
            *(float4*)&inT[r][q + 0]  = z4;
            *(float4*)&inT[r][q + 4]  = z4;
            *(float4*)&inT[r][q + 8]  = z4;
            *(float4*)&inT[r][q + 12] = z4;
        }
        if (t < 12) {
            const int r2 = 64 + (t >> 2);      // 64..66
            const int l2 = lt0 + r2 - 3;       // = lt0 + 61..63, always >= 0
            const float* src = xpre + ((size_t)(b * 1024 + l2)) * 2048 + d0 + q;
            *(float4*)&inT[r2][q + 0]  = *(const float4*)(src + 0);
            *(float4*)&inT[r2][q + 4]  = *(const float4*)(src + 4);
            *(float4*)&inT[r2][q + 8]  = *(const float4*)(src + 8);
            *(float4*)&inT[r2][q + 12] = *(const float4*)(src + 12);
        }
    }
    __syncthreads();

    const int dl = t & 63;
    const int seg = t >> 6;
    const int d = d0 + dl;
    const float w0 = conv_w[d * 4 + 0], w1 = conv_w[d * 4 + 1];
    const float w2 = conv_w[d * 4 + 2], w3 = conv_w[d * 4 + 3];
    const float bias = conv_b[d];

    float p[19];
#pragma unroll
    for (int j = 0; j < 19; ++j) p[j] = inT[seg * 16 + j][dl];
#pragma unroll
    for (int j = 0; j < 16; ++j) {
        float v = siluf(bias + w0 * p[j] + w1 * p[j + 1] + w2 * p[j + 2] + w3 * p[j + 3]);
        tile[seg * 16 + j][dl] = f2bf(v);
    }
    __syncthreads();

    const int ml = t >> 2;
    const int c = t & 3;
    short8 s0 = *(const short8*)&tile[ml][c * 16];
    short8 s1 = *(const short8*)&tile[ml][c * 16 + 8];
    unsigned short* dst = x_bf + (size_t)(b * 1024 + lt0 + ml) * 2048 + d0 + c * 16;
    *(short8*)dst = s0;
    *(short8*)(dst + 8) = s1;
}

// ---- fused dt tile: dt[l][d'] for a (32 l x 256 d) block, computed by MFMA ----
// Same intrinsic, slice order (k 0..31 then 32..63), bias+softplus formula, and
// C/D mapping as the old dt_gemm -> bit-identical dt values. Waves index N.
__device__ __forceinline__ void dt_tile(
    const unsigned short* __restrict__ sp64,  // [2048 m][64] bf16
    const unsigned short* __restrict__ Wdt,   // [2048 d][64] bf16
    const float* __restrict__ bias,           // b_dt [2048]
    int mb, int d0, int lane, int wave, int lr, int quad,
    float (*dtile)[260])
{
    floatx4 acc[2][4];
#pragma unroll
    for (int mi = 0; mi < 2; ++mi)
#pragma unroll
        for (int ni = 0; ni < 4; ++ni)
            acc[mi][ni] = (floatx4){0.f, 0.f, 0.f, 0.f};

#pragma unroll
    for (int s = 0; s < 2; ++s) {
        short8 af[2], bf[4];
#pragma unroll
        for (int mi = 0; mi < 2; ++mi)
            af[mi] = *(const short8*)&sp64[(size_t)(mb + mi * 16 + lr) * 64 + s * 32 + quad * 8];
#pragma unroll
        for (int ni = 0; ni < 4; ++ni)
            bf[ni] = *(const short8*)&Wdt[(size_t)(d0 + wave * 64 + ni * 16 + lr) * 64 + s * 32 + quad * 8];
#pragma unroll
        for (int mi = 0; mi < 2; ++mi)
#pragma unroll
            for (int ni = 0; ni < 4; ++ni)
                acc[mi][ni] = __builtin_amdgcn_mfma_f32_16x16x32_bf16(
                    af[mi], bf[ni], acc[mi][ni], 0, 0, 0);
    }

#pragma unroll
    for (int ni = 0; ni < 4; ++ni) {
        const int cc = wave * 64 + ni * 16 + lr;
        const float bv = bias[d0 + cc];
#pragma unroll
        for (int mi = 0; mi < 2; ++mi)
#pragma unroll
            for (int r = 0; r < 4; ++r) {
                const float z = acc[mi][ni][r] + bv;
                const float spv = fmaxf(z, 0.f) + __logf(1.f + __expf(-fabsf(z)));
                dtile[mi * 16 + quad * 4 + r][cc] = spv;
            }
    }
}

// ---------------- scan pass 1: fused dt + per-chunk H[n] + dt-sum scalar --------
__global__ __launch_bounds__(256) void scan_p1(
    const unsigned short* __restrict__ sp64, const unsigned short* __restrict__ Wdt,
    const float* __restrict__ b_dt, const unsigned short* __restrict__ x_bf,
    const float* __restrict__ sp, const float* __restrict__ A_log,
    float* __restrict__ Dts, float* __restrict__ Hch)
{
    __shared__ float sB[CL][16];
    __shared__ float dtile[CL][260];
    const int tid = threadIdx.x;
    const int lane = tid & 63;
    const int wave = tid >> 6;
    const int lr = lane & 15;
    const int quad = lane >> 4;
    const int d0 = blockIdx.x * 256;
    const int d = d0 + tid;
    const int ck = blockIdx.y;
    const int b = blockIdx.z;
    const int mb = b * 1024 + ck * CL;

    dt_tile(sp64, Wdt, b_dt, mb, d0, lane, wave, lr, quad, dtile);

    if (tid < CL * 4) {
        int row = tid >> 2, q = (tid & 3) * 4;
        *(float4*)&sB[row][q] = *(const float4*)(sp + (size_t)(mb + row) * 96 + 64 + q);
    }
    float An2[16];
    {
        const float* al = A_log + d * 16;
#pragma unroll
        for (int j = 0; j < 16; j += 4) {
            float4 a4 = *(const float4*)(al + j);
            An2[j + 0] = -__expf(a4.x) * 1.44269504f;
            An2[j + 1] = -__expf(a4.y) * 1.44269504f;
            An2[j + 2] = -__expf(a4.z) * 1.44269504f;
            An2[j + 3] = -__expf(a4.w) * 1.44269504f;
        }
    }
    __syncthreads();

    float h[16];
#pragma unroll
    for (int n = 0; n < 16; ++n) h[n] = 0.f;
    float dts = 0.f;

    for (int l = 0; l < CL; ++l) {
        const size_t off = (size_t)(mb + l) * 2048 + d;
        const float dtv = dtile[l][tid];
        const float xv = bf2f(x_bf[off]);
        const float u = dtv * xv;
        dts += dtv;
        float4 B0 = *(const float4*)&sB[l][0];
        float4 B1 = *(const float4*)&sB[l][4];
        float4 B2 = *(const float4*)&sB[l][8];
        float4 B3 = *(const float4*)&sB[l][12];
        float Bv[16] = {B0.x, B0.y, B0.z, B0.w, B1.x, B1.y, B1.z, B1.w,
                        B2.x, B2.y, B2.z, B2.w, B3.x, B3.y, B3.z, B3.w};
#pragma unroll
        for (int n = 0; n < 16; ++n) {
            const float dA = __builtin_amdgcn_exp2f(dtv * An2[n]);
            h[n] = fmaf(dA, h[n], Bv[n] * u);
        }
    }

    const size_t cb = (size_t)(b * NCK + ck) * 2048 + d;
    Dts[cb] = dts;
    const size_t base = cb * 16;
#pragma unroll
    for (int j = 0; j < 16; j += 4)
        *(float4*)(Hch + base + j) = make_float4(h[j], h[j + 1], h[j + 2], h[j + 3]);
}

// ---------------- scan combine: serial over chunks; recompute P from dts ------
__global__ __launch_bounds__(256) void scan_combine(
    const float* __restrict__ Dts, const float* __restrict__ Hch,
    const float* __restrict__ A_log, float* __restrict__ Hin)
{
    const int flat = blockIdx.x * 256 + threadIdx.x;   // 2*2048*16
    const int dn = flat & 32767;
    const int b = flat >> 15;
    const int d = dn >> 4;
    const float An2 = -__expf(A_log[dn]) * 1.44269504f;
    float hin = 0.f;
#pragma unroll 4
    for (int ck = 0; ck < NCK; ++ck) {
        const size_t cb = (size_t)(b * NCK + ck) * 2048 + d;
        const float p = __builtin_amdgcn_exp2f(Dts[cb] * An2);
        const size_t a = ((size_t)(b * NCK + ck) << 15) + dn;
        const float hc = Hch[a];
        Hin[a] = hin;
        hin = fmaf(p, hin, hc);
    }
}

// ---------------- scan pass 2: fused dt + rescan with h_in + gating -> y_bf ----
__global__ __launch_bounds__(256) void scan_p2(
    const unsigned short* __restrict__ sp64, const unsigned short* __restrict__ Wdt,
    const float* __restrict__ b_dt, const unsigned short* __restrict__ x_bf,
    const float* __restrict__ gate, const float* __restrict__ sp,
    const float* __restrict__ A_log, const float* __restrict__ Dp,
    const float* __restrict__ Hin, unsigned short* __restrict__ y_bf)
{
    __shared__ float sBC[CL][32];
    __shared__ float dtile[CL][260];
    const int tid = threadIdx.x;
    const int lane = tid & 63;
    const int wave = tid >> 6;
    const int lr = lane & 15;
    const int quad = lane >> 4;
    const int d0 = blockIdx.x * 256;
    const int d = d0 + tid;
    const int ck = blockIdx.y;
    const int b = blockIdx.z;
    const int mb = b * 1024 + ck * CL;

    dt_tile(sp64, Wdt, b_dt, mb, d0, lane, wave, lr, quad, dtile);

    {
        int row = tid >> 3, q = (tid & 7) * 4;
        *(float4*)&sBC[row][q] = *(const float4*)(sp + (size_t)(mb + row) * 96 + 64 + q);
    }
    float An2[16];
    {
        const float* al = A_log + d * 16;
#pragma unroll
        for (int j = 0; j < 16; j += 4) {
            float4 a4 = *(const float4*)(al + j);
            An2[j + 0] = -__expf(a4.x) * 1.44269504f;
            An2[j + 1] = -__expf(a4.y) * 1.44269504f;
            An2[j + 2] = -__expf(a4.z) * 1.44269504f;
            An2[j + 3] = -__expf(a4.w) * 1.44269504f;
        }
    }
    float h[16];
    {
        const size_t base = ((size_t)(b * NCK + ck) * 2048 + d) * 16;
#pragma unroll
        for (int j = 0; j < 16; j += 4) {
            float4 hv = *(const float4*)(Hin + base + j);
            h[j] = hv.x; h[j + 1] = hv.y; h[j + 2] = hv.z; h[j + 3] = hv.w;
        }
    }
    const float Dv = Dp[d];
    __syncthreads();

    for (int l = 0; l < CL; ++l) {
        const size_t off = (size_t)(mb + l) * 2048 + d;
        const float dtv = dtile[l][tid];
        const float xv = bf2f(x_bf[off]);
        const float gv = gate[off];
        const float u = dtv * xv;
        float4 B0 = *(const float4*)&sBC[l][0];
        float4 B1 = *(const float4*)&sBC[l][4];
        float4 B2 = *(const float4*)&sBC[l][8];
        float4 B3 = *(const float4*)&sBC[l][12];
        float Bv[16] = {B0.x, B0.y, B0.z, B0.w, B1.x, B1.y, B1.z, B1.w,
                        B2.x, B2.y, B2.z, B2.w, B3.x, B3.y, B3.z, B3.w};
#pragma unroll
        for (int n = 0; n < 16; ++n) {
            const float dA = __builtin_amdgcn_exp2f(dtv * An2[n]);
            h[n] = fmaf(dA, h[n], Bv[n] * u);
        }
        float4 C0 = *(const float4*)&sBC[l][16];
        float4 C1 = *(const float4*)&sBC[l][20];
        float4 C2 = *(const float4*)&sBC[l][24];
        float4 C3 = *(const float4*)&sBC[l][28];
        float Cv[16] = {C0.x, C0.y, C0.z, C0.w, C1.x, C1.y, C1.z, C1.w,
                        C2.x, C2.y, C2.z, C2.w, C3.x, C3.y, C3.z, C3.w};
        float p = 0.f;
#pragma unroll
        for (int n = 0; n < 16; ++n)
            p = fmaf(h[n], Cv[n], p);
        y_bf[off] = f2bf(fmaf(xv, Dv, p) * siluf(gv));
    }
}

extern "C" void kernel_launch(void* const* d_in, const int* in_sizes, int n_in,
                              void* d_out, int out_size, void* d_ws, size_t ws_size,
                              hipStream_t stream)
{
    const float* hs     = (const float*)d_in[0];
    const float* W_in   = (const float*)d_in[1];
    const float* conv_w = (const float*)d_in[2];
    const float* conv_b = (const float*)d_in[3];
    const float* W_x    = (const float*)d_in[4];
    const float* W_dt   = (const float*)d_in[5];
    const float* b_dt   = (const float*)d_in[6];
    const float* A_log  = (const float*)d_in[7];
    const float* Dp     = (const float*)d_in[8];
    const float* W_out  = (const float*)d_in[9];
    float* out = (float*)d_out;

    // workspace (~78 MB live) with overlays (dtb slot now unused — dt fused into scans)
    float* ws    = (float*)d_ws;
    float* gate  = ws;                               // [2048 m][2048 d] f32
    float* dtb   = gate + (size_t)4194304;           // (unused)
    float* xpre  = dtb + (size_t)4194304;            // [2048 m][2048 d] f32 (dead after conv)
    float* ssm_p = xpre + (size_t)4194304;           // [2048 m][96] f32
    unsigned short* hs_bf    = (unsigned short*)(ssm_p + 196608);   // 2048*1024
    unsigned short* W_in_bf  = hs_bf + (size_t)2097152;             // 4096*1024
    unsigned short* W_out_bf = W_in_bf + (size_t)4194304;           // 1024*2048
    unsigned short* W_x_bf   = W_out_bf + (size_t)2097152;          // 96*2048
    unsigned short* W_dt_bf  = W_x_bf + (size_t)196608;             // 2048*64
    unsigned short* sp64_bf  = W_dt_bf + (size_t)131072;            // 2048*64
    unsigned short* x_bf     = sp64_bf + (size_t)131072;            // [2048 m][2048 d]
    float* Dts  = (float*)(x_bf + (size_t)4194304);   // [2*32][2048] dt-sums (0.5 MB)
    float* P1   = xpre;                               // overlay: ssm partials 16*2048*96
    float* Hin  = xpre;                               // overlay after reduce_ssm: 2*32*2048*16
    float* Hch  = xpre + (size_t)2097152;             // overlay
    float* Pout = gate;                               // overlay after scan_p2 (gate dead)
    unsigned short* y_bf = hs_bf;                     // overlay (hs_bf+W_in_bf dead)

    const int M = B_ * L_;  // 2048

    // 0. fused fp32 -> bf16 converts (hs, W_in, W_out, W_x, W_dt)
    cvt_all<<<(Q4 + 255) / 256, 256, 0, stream>>>(
        hs, W_in, W_out, W_x, W_dt, hs_bf, W_in_bf, W_out_bf, W_x_bf, W_dt_bf);

    // 1. proj GEMM: 128x128 fat-wave tile, BK=64 -> 512 blocks (XCD-swizzled), nt=16
    gemm128<4><<<dim3(4096 / 128, M / 128, 1), 256, 0, stream>>>(
        hs_bf, W_in_bf, xpre, 1024, 2048, 1024, 0, gate);

    // 2. conv + SiLU (m-major in via LDS stage) -> x_bf[m][d]
    conv_silu_kernel<<<dim3(D_ / 64, L_ / 64, B_), 256, 0, stream>>>(
        xpre, conv_w, conv_b, x_bf);

    // 3. ssm partials: P1[z][m][96] = x @ W_x^T (K-chunk 128, 16 splits, nt=2)
    gemm_ssm<<<dim3(1, M / 64, 16), 256, 0, stream>>>(
        x_bf, W_x_bf, P1, 2048, 96, 96, 128, 96, (size_t)2048 * 96);

    // 3b. reduce 16 partials -> ssm_p[m][96] + sp64_bf[m][64]
    reduce_ssm<<<(2048 * 24) / 256, 256, 0, stream>>>(P1, ssm_p, sp64_bf);

    // 4+5. scan with fused dt: pass1 -> combine -> pass2 (writes y_bf[m][d])
    scan_p1<<<dim3(D_ / 256, NCK, B_), 256, 0, stream>>>(
        sp64_bf, W_dt_bf, b_dt, x_bf, ssm_p, A_log, Dts, Hch);
    scan_combine<<<(B_ * D_ * 16) / 256, 256, 0, stream>>>(Dts, Hch, A_log, Hin);
    scan_p2<<<dim3(D_ / 256, NCK, B_), 256, 0, stream>>>(
        sp64_bf, W_dt_bf, b_dt, x_bf, gate, ssm_p, A_log, Dp, Hin, y_bf);

    // 6. out partials: 128x128 fat-wave, K-chunk 512, 4 splits -> 512 blocks (swizzled)
    gemm128<0><<<dim3(1024 / 128, M / 128, 4), 256, 0, stream>>>(
        y_bf, W_out_bf, Pout, 2048, 1024, 512, (size_t)2048 * 1024, nullptr);

    // 6b. reduce 4 partials -> out
    reduce_out<<<(2048 * 1024 / 4) / 256, 256, 0, stream>>>(Pout, out);
}

// Round 13
// 210.575 us; speedup vs baseline: 1.0676x; 1.0046x over previous
//
#include <hip/hip_runtime.h>
#include <hip/hip_bf16.h>
#include <math.h>

#define B_ 2
#define L_ 1024
#define H_ 1024
#define D_ 2048
#define N_ 16
#define R_ 64
#define NCK 32     // chunks per sequence
#define CL 32      // chunk length (NCK*CL == L_)

typedef short short8 __attribute__((ext_vector_type(8)));
typedef float floatx4 __attribute__((ext_vector_type(4)));

__device__ __forceinline__ float siluf(float g) {
    return g / (1.0f + __expf(-g));
}

__device__ __forceinline__ unsigned short f2bf(float f) {
    unsigned int u = __float_as_uint(f);
    u = (u + 0x7fffu + ((u >> 16) & 1u)) >> 16;  // RNE
    return (unsigned short)u;
}

__device__ __forceinline__ float bf2f(unsigned short u) {
    return __uint_as_float(((unsigned int)u) << 16);
}

// async global->LDS, 16B per lane; lds base must be wave-uniform
__device__ __forceinline__ void gl2lds(const unsigned short* g, unsigned short* l) {
    __builtin_amdgcn_global_load_lds(
        (const __attribute__((address_space(1))) unsigned int*)g,
        (__attribute__((address_space(3))) unsigned int*)l, 16, 0, 0);
}

// ---------------- fused fp32 -> bf16 convert for all 5 static tensors ----------------
#define Q0 524288    // hs        2048*1024 /4
#define Q1 1572864   // + W_in    4096*1024 /4
#define Q2 2097152   // + W_out   1024*2048 /4
#define Q3 2146304   // + W_x     96*2048   /4
#define Q4 2179072   // + W_dt    2048*64   /4
__global__ __launch_bounds__(256) void cvt_all(
    const float* __restrict__ i0, const float* __restrict__ i1,
    const float* __restrict__ i2, const float* __restrict__ i3,
    const float* __restrict__ i4,
    unsigned short* __restrict__ o0, unsigned short* __restrict__ o1,
    unsigned short* __restrict__ o2, unsigned short* __restrict__ o3,
    unsigned short* __restrict__ o4)
{
    int q = blockIdx.x * 256 + threadIdx.x;
    if (q >= Q4) return;
    const float* in; unsigned short* out; int base;
    if (q < Q0)      { in = i0; out = o0; base = 0; }
    else if (q < Q1) { in = i1; out = o1; base = Q0; }
    else if (q < Q2) { in = i2; out = o2; base = Q1; }
    else if (q < Q3) { in = i3; out = o3; base = Q2; }
    else             { in = i4; out = o4; base = Q3; }
    int i = (q - base) * 4;
    float4 v = *(const float4*)(in + i);
    ushort4 o;
    o.x = f2bf(v.x); o.y = f2bf(v.y); o.z = f2bf(v.z); o.w = f2bf(v.w);
    *(ushort4*)(out + i) = o;
}

// ---------------- fat-wave GEMM: C = A[M,K] @ B[N,K]^T, 128x128 tile, BK=64 -------
// 256 threads, 4 waves as 2x2, each wave 64x64 output (4x4 frags of 16x16x32).
// FLOP per LDS byte = 32. Double-buffered LDS (64 KB), depth-1 prefetch, counted
// vmcnt(8), raw s_barrier. Rule-21 swizzle: LDS linear, source col-slot and read
// col-slot both XOR (row&7) over the 8 16B slots. N multiple of 128, K mult of 64.
// XCD swizzle (T1): bijective remap (nwg must be divisible by 8).
// EPI: 0 = split-K partial store C[z*partStride + m*ldc + n],
//      4 = proj: n<2048 -> C[m][n] (xpre); n>=2048 -> C2[m][n-2048] (gate)
template<int EPI>
__global__ __launch_bounds__(256) void gemm128(
    const unsigned short* __restrict__ A, const unsigned short* __restrict__ Bm,
    float* __restrict__ C, int K, int ldc, int kChunk,
    size_t partStride, float* __restrict__ C2)
{
    __shared__ unsigned short As[2][128 * 64];
    __shared__ unsigned short Bs[2][128 * 64];
    const int tid  = threadIdx.x;
    const int lane = tid & 63;
    const int wave = tid >> 6;
    const int wm = (wave >> 1) * 64;
    const int wn = (wave & 1) * 64;
    const int lr   = lane & 15;
    const int quad = lane >> 4;

    // XCD-aware bijective block swizzle (nwg % 8 == 0 for all call sites)
    const int nwg = gridDim.x * gridDim.y * gridDim.z;
    const int lin = blockIdx.x + gridDim.x * (blockIdx.y + gridDim.y * blockIdx.z);
    const int swz = (lin & 7) * (nwg >> 3) + (lin >> 3);
    const int bx  = swz % gridDim.x;
    const int tmp = swz / gridDim.x;
    const int by  = tmp % gridDim.y;
    const int bz  = tmp / gridDim.y;

    const int m0 = by * 128;
    const int n0 = bx * 128;
    const int k0 = bz * kChunk;

    const int rowIn8 = lane >> 3;
    const int colSw  = ((lane & 7) ^ rowIn8) * 8;
    const int srow   = wave * 8 + rowIn8;               // 0..31
    const size_t aoff0 = (size_t)(m0 + srow +  0) * K + colSw;
    const size_t aoff1 = (size_t)(m0 + srow + 32) * K + colSw;
    const size_t aoff2 = (size_t)(m0 + srow + 64) * K + colSw;
    const size_t aoff3 = (size_t)(m0 + srow + 96) * K + colSw;
    const size_t boff0 = (size_t)(n0 + srow +  0) * K + colSw;
    const size_t boff1 = (size_t)(n0 + srow + 32) * K + colSw;
    const size_t boff2 = (size_t)(n0 + srow + 64) * K + colSw;
    const size_t boff3 = (size_t)(n0 + srow + 96) * K + colSw;
    const int rq0 = ((quad) ^ (lr & 7)) * 8;
    const int rq1 = rq0 ^ 32;

    floatx4 acc[4][4];
#pragma unroll
    for (int mi = 0; mi < 4; ++mi)
#pragma unroll
        for (int ni = 0; ni < 4; ++ni)
            acc[mi][ni] = (floatx4){0.f, 0.f, 0.f, 0.f};

#define STG(buf, kt)                                                    \
    do {                                                                \
        gl2lds(A + aoff0 + (kt), &As[buf][(0  + wave * 8) * 64]);       \
        gl2lds(A + aoff1 + (kt), &As[buf][(32 + wave * 8) * 64]);       \
        gl2lds(A + aoff2 + (kt), &As[buf][(64 + wave * 8) * 64]);       \
        gl2lds(A + aoff3 + (kt), &As[buf][(96 + wave * 8) * 64]);       \
        gl2lds(Bm + boff0 + (kt), &Bs[buf][(0  + wave * 8) * 64]);      \
        gl2lds(Bm + boff1 + (kt), &Bs[buf][(32 + wave * 8) * 64]);      \
        gl2lds(Bm + boff2 + (kt), &Bs[buf][(64 + wave * 8) * 64]);      \
        gl2lds(Bm + boff3 + (kt), &Bs[buf][(96 + wave * 8) * 64]);      \
    } while (0)

    STG(0, k0);

    const int nt = kChunk >> 6;
    for (int t = 0; t < nt; ++t) {
        const int cur = t & 1;
        if (t + 1 < nt) {
            STG(cur ^ 1, k0 + (t + 1) * 64);
            asm volatile("s_waitcnt vmcnt(8)" ::: "memory");  // tile t landed; t+1 in flight
        } else {
            asm volatile("s_waitcnt vmcnt(0)" ::: "memory");
        }
        __builtin_amdgcn_s_barrier();          // all waves see tile t in LDS
        __builtin_amdgcn_sched_barrier(0);     // pin: no LDS reads hoisted above

        short8 a0f[4], a1f[4], b0f[4], b1f[4];
#pragma unroll
        for (int mi = 0; mi < 4; ++mi) {
            a0f[mi] = *(const short8*)&As[cur][(wm + mi * 16 + lr) * 64 + rq0];
            a1f[mi] = *(const short8*)&As[cur][(wm + mi * 16 + lr) * 64 + rq1];
        }
#pragma unroll
        for (int ni = 0; ni < 4; ++ni) {
            b0f[ni] = *(const short8*)&Bs[cur][(wn + ni * 16 + lr) * 64 + rq0];
            b1f[ni] = *(const short8*)&Bs[cur][(wn + ni * 16 + lr) * 64 + rq1];
        }
#pragma unroll
        for (int mi = 0; mi < 4; ++mi)
#pragma unroll
            for (int ni = 0; ni < 4; ++ni)
                acc[mi][ni] = __builtin_amdgcn_mfma_f32_16x16x32_bf16(
                    a0f[mi], b0f[ni], acc[mi][ni], 0, 0, 0);
#pragma unroll
        for (int mi = 0; mi < 4; ++mi)
#pragma unroll
            for (int ni = 0; ni < 4; ++ni)
                acc[mi][ni] = __builtin_amdgcn_mfma_f32_16x16x32_bf16(
                    a1f[mi], b1f[ni], acc[mi][ni], 0, 0, 0);

        asm volatile("s_waitcnt lgkmcnt(0)" ::: "memory");  // this wave's reads retired
        __builtin_amdgcn_s_barrier();          // safe for next stage to overwrite cur
    }
#undef STG

    float* Cz = C + (size_t)bz * partStride;
#pragma unroll
    for (int mi = 0; mi < 4; ++mi)
#pragma unroll
        for (int ni = 0; ni < 4; ++ni) {
            const int rr = m0 + wm + mi * 16 + quad * 4;
            const int cc = n0 + wn + ni * 16 + lr;
            if (EPI == 4) {
                if (cc < 2048) {
#pragma unroll
                    for (int r = 0; r < 4; ++r)
                        C[(size_t)(rr + r) * 2048 + cc] = acc[mi][ni][r];
                } else {
#pragma unroll
                    for (int r = 0; r < 4; ++r)
                        C2[(size_t)(rr + r) * 2048 + (cc - 2048)] = acc[mi][ni][r];
                }
            } else {
#pragma unroll
                for (int r = 0; r < 4; ++r)
                    Cz[(size_t)(rr + r) * ldc + cc] = acc[mi][ni][r];
            }
        }
}

// ---------------- narrow GEMM (ssm): C = A[M,K] @ B[N,K]^T, 64x128 tile, BK=64 ----
// 4 waves as 2m x 2n, wave 32x64; counted vmcnt(6); row-clamped B (N=96).
__global__ __launch_bounds__(256) void gemm_ssm(
    const unsigned short* __restrict__ A, const unsigned short* __restrict__ Bm,
    float* __restrict__ C, int K, int Ncols, int ldc, int kChunk, int nMax,
    size_t partStride)
{
    __shared__ unsigned short As[2][64 * 64];
    __shared__ unsigned short Bs[2][128 * 64];
    const int tid  = threadIdx.x;
    const int lane = tid & 63;
    const int wave = tid >> 6;
    const int wm = (wave >> 1) * 32;
    const int wn = (wave & 1) * 64;
    const int lr   = lane & 15;
    const int quad = lane >> 4;
    const int m0 = blockIdx.y * 64;
    const int n0 = blockIdx.x * 128;
    const int k0 = blockIdx.z * kChunk;

    const int rowIn8 = lane >> 3;
    const int colSw  = ((lane & 7) ^ rowIn8) * 8;
    const size_t aoff0 = (size_t)(m0 + 0  + wave * 8 + rowIn8) * K + colSw;
    const size_t aoff1 = (size_t)(m0 + 32 + wave * 8 + rowIn8) * K + colSw;
    const size_t boff0 = (size_t)min(n0 + 0  + wave * 8 + rowIn8, nMax - 1) * K + colSw;
    const size_t boff1 = (size_t)min(n0 + 32 + wave * 8 + rowIn8, nMax - 1) * K + colSw;
    const size_t boff2 = (size_t)min(n0 + 64 + wave * 8 + rowIn8, nMax - 1) * K + colSw;
    const size_t boff3 = (size_t)min(n0 + 96 + wave * 8 + rowIn8, nMax - 1) * K + colSw;
    const int rq0 = ((quad) ^ (lr & 7)) * 8;
    const int rq1 = rq0 ^ 32;

    floatx4 acc[2][4];
#pragma unroll
    for (int mi = 0; mi < 2; ++mi)
#pragma unroll
        for (int ni = 0; ni < 4; ++ni)
            acc[mi][ni] = (floatx4){0.f, 0.f, 0.f, 0.f};

#define STAGE(buf, kt)                                                   \
    do {                                                                 \
        gl2lds(A + aoff0 + (kt), &As[buf][(0  + wave * 8) * 64]);        \
        gl2lds(A + aoff1 + (kt), &As[buf][(32 + wave * 8) * 64]);        \
        gl2lds(Bm + boff0 + (kt), &Bs[buf][(0   + wave * 8) * 64]);      \
        gl2lds(Bm + boff1 + (kt), &Bs[buf][(32  + wave * 8) * 64]);      \
        gl2lds(Bm + boff2 + (kt), &Bs[buf][(64  + wave * 8) * 64]);      \
        gl2lds(Bm + boff3 + (kt), &Bs[buf][(96  + wave * 8) * 64]);      \
    } while (0)

    STAGE(0, k0);

    const int nt = kChunk >> 6;
    for (int t = 0; t < nt; ++t) {
        const int cur = t & 1;
        if (t + 1 < nt) {
            STAGE(cur ^ 1, k0 + (t + 1) * 64);
            asm volatile("s_waitcnt vmcnt(6)" ::: "memory");
        } else {
            asm volatile("s_waitcnt vmcnt(0)" ::: "memory");
        }
        __builtin_amdgcn_s_barrier();
        __builtin_amdgcn_sched_barrier(0);

        short8 a0[2], a1[2], b0[4], b1[4];
#pragma unroll
        for (int mi = 0; mi < 2; ++mi) {
            a0[mi] = *(const short8*)&As[cur][(wm + mi * 16 + lr) * 64 + rq0];
            a1[mi] = *(const short8*)&As[cur][(wm + mi * 16 + lr) * 64 + rq1];
        }
#pragma unroll
        for (int ni = 0; ni < 4; ++ni) {
            b0[ni] = *(const short8*)&Bs[cur][(wn + ni * 16 + lr) * 64 + rq0];
            b1[ni] = *(const short8*)&Bs[cur][(wn + ni * 16 + lr) * 64 + rq1];
        }
#pragma unroll
        for (int mi = 0; mi < 2; ++mi)
#pragma unroll
            for (int ni = 0; ni < 4; ++ni)
                acc[mi][ni] = __builtin_amdgcn_mfma_f32_16x16x32_bf16(
                    a0[mi], b0[ni], acc[mi][ni], 0, 0, 0);
#pragma unroll
        for (int mi = 0; mi < 2; ++mi)
#pragma unroll
            for (int ni = 0; ni < 4; ++ni)
                acc[mi][ni] = __builtin_amdgcn_mfma_f32_16x16x32_bf16(
                    a1[mi], b1[ni], acc[mi][ni], 0, 0, 0);

        asm volatile("s_waitcnt lgkmcnt(0)" ::: "memory");
        __builtin_amdgcn_s_barrier();
    }
#undef STAGE

    float* Cz = C + (size_t)blockIdx.z * partStride;
#pragma unroll
    for (int mi = 0; mi < 2; ++mi)
#pragma unroll
        for (int ni = 0; ni < 4; ++ni) {
            const int rr = m0 + wm + mi * 16 + quad * 4;
            const int cc = n0 + wn + ni * 16 + lr;
            if (cc >= Ncols) continue;
#pragma unroll
            for (int r = 0; r < 4; ++r)
                Cz[(size_t)(rr + r) * ldc + cc] = acc[mi][ni][r];
        }
}

// ---------------- reduce 16 ssm partials -> ssm_p[m][96] + sp64_bf[m][64] ----------------
__global__ __launch_bounds__(256) void reduce_ssm(
    const float* __restrict__ P, float* __restrict__ ssm_p,
    unsigned short* __restrict__ sp64)
{
    const int q = blockIdx.x * 256 + threadIdx.x;    // 2048*24 quads
    const int m = q / 24;
    const int c = (q - m * 24) * 4;
    const size_t idx = (size_t)m * 96 + c;
    float4 s = make_float4(0.f, 0.f, 0.f, 0.f);
#pragma unroll
    for (int z = 0; z < 16; ++z) {
        float4 v = *(const float4*)(P + (size_t)z * (2048 * 96) + idx);
        s.x += v.x; s.y += v.y; s.z += v.z; s.w += v.w;
    }
    *(float4*)(ssm_p + idx) = s;
    if (c < 64) {
        ushort4 o;
        o.x = f2bf(s.x); o.y = f2bf(s.y); o.z = f2bf(s.z); o.w = f2bf(s.w);
        *(ushort4*)(sp64 + (size_t)m * 64 + c) = o;
    }
}

// ---------------- reduce 4 out partials -> out[m][h] ----------------
__global__ __launch_bounds__(256) void reduce_out(
    const float* __restrict__ P, float* __restrict__ out)
{
    const size_t i = ((size_t)blockIdx.x * 256 + threadIdx.x) * 4;  // 2048*1024 total
    float4 a = *(const float4*)(P + i);
    float4 b = *(const float4*)(P + 2097152 + i);
    float4 c = *(const float4*)(P + 2 * 2097152 + i);
    float4 d = *(const float4*)(P + 3 * 2097152 + i);
    *(float4*)(out + i) = make_float4(a.x + b.x + c.x + d.x,
                                      a.y + b.y + c.y + d.y,
                                      a.z + b.z + c.z + d.z,
                                      a.w + b.w + c.w + d.w);
}

// ---------------- causal depthwise conv (K=4) + bias + SiLU, m-major f32 in ------
// xpre[m][d] staged through LDS: coalesced global reads, conflict-free LDS reads.
__global__ __launch_bounds__(256) void conv_silu_kernel(
    const float* __restrict__ xpre, const float* __restrict__ conv_w,
    const float* __restrict__ conv_b, unsigned short* __restrict__ x_bf)
{
    __shared__ float inT[67][64];            // rows r <-> l = lt0 + r - 3
    __shared__ unsigned short tile[64][72];  // out staging for coalesced store
    const int t = threadIdx.x;
    const int d0 = blockIdx.x * 64;
    const int lt0 = blockIdx.y * 64;
    const int b = blockIdx.z;

    {
        const int r = t >> 2;          // 0..63
        const int q = (t & 3) * 16;    // 0,16,32,48
        const int l = lt0 + r - 3;
        if (l >= 0) {
            const float* src = xpre + ((size_t)(b * 1024 + l)) * 2048 + d0 + q;
            *(float4*)&inT[r][q + 0]  = *(const float4*)(src + 0);
            *(float4*)&inT[r][q + 4]  = *(const float4*)(src + 4);
            *(float4*)&inT[r][q + 8]  = *(const float4*)(src + 8);
            *(float4*)&inT[r][q + 12] = *(const float4*)(src + 12);
        } else {
            float4 z4 = make_float4(0.f, 0.f, 0.f, 0.f);
            *(float4*)&inT[r][q + 0]  = z4;
            *(float4*)&inT[r][q + 4]  = z4;
            *(float4*)&inT[r][q + 8]  = z4;
            *(float4*)&inT[r][q + 12] = z4;
        }
        if (t < 12) {
            const int r2 = 64 + (t >> 2);      // 64..66
            const int l2 = lt0 + r2 - 3;       // = lt0 + 61..63, always >= 0
            const float* src = xpre + ((size_t)(b * 1024 + l2)) * 2048 + d0 + q;
            *(float4*)&inT[r2][q + 0]  = *(const float4*)(src + 0);
            *(float4*)&inT[r2][q + 4]  = *(const float4*)(src + 4);
            *(float4*)&inT[r2][q + 8]  = *(const float4*)(src + 8);
            *(float4*)&inT[r2][q + 12] = *(const float4*)(src + 12);
        }
    }
    __syncthreads();

    const int dl = t & 63;
    const int seg = t >> 6;
    const int d = d0 + dl;
    const float w0 = conv_w[d * 4 + 0], w1 = conv_w[d * 4 + 1];
    const float w2 = conv_w[d * 4 + 2], w3 = conv_w[d * 4 + 3];
    const float bias = conv_b[d];

    float p[19];
#pragma unroll
    for (int j = 0; j < 19; ++j) p[j] = inT[seg * 16 + j][dl];
#pragma unroll
    for (int j = 0; j < 16; ++j) {
        float v = siluf(bias + w0 * p[j] + w1 * p[j + 1] + w2 * p[j + 2] + w3 * p[j + 3]);
        tile[seg * 16 + j][dl] = f2bf(v);
    }
    __syncthreads();

    const int ml = t >> 2;
    const int c = t & 3;
    short8 s0 = *(const short8*)&tile[ml][c * 16];
    short8 s1 = *(const short8*)&tile[ml][c * 16 + 8];
    unsigned short* dst = x_bf + (size_t)(b * 1024 + lt0 + ml) * 2048 + d0 + c * 16;
    *(short8*)dst = s0;
    *(short8*)(dst + 8) = s1;
}

// ---- fused dt tile: dt[l][d'] for a (32 l x 256 d) block, computed by MFMA ----
// Same intrinsic, slice order (k 0..31 then 32..63), bias+softplus formula, and
// C/D mapping as the old dt_gemm -> bit-identical dt values. Waves index N.
__device__ __forceinline__ void dt_tile(
    const unsigned short* __restrict__ sp64,  // [2048 m][64] bf16
    const unsigned short* __restrict__ Wdt,   // [2048 d][64] bf16
    const float* __restrict__ bias,           // b_dt [2048]
    int mb, int d0, int lane, int wave, int lr, int quad,
    float (*dtile)[260])
{
    floatx4 acc[2][4];
#pragma unroll
    for (int mi = 0; mi < 2; ++mi)
#pragma unroll
        for (int ni = 0; ni < 4; ++ni)
            acc[mi][ni] = (floatx4){0.f, 0.f, 0.f, 0.f};

#pragma unroll
    for (int s = 0; s < 2; ++s) {
        short8 af[2], bf[4];
#pragma unroll
        for (int mi = 0; mi < 2; ++mi)
            af[mi] = *(const short8*)&sp64[(size_t)(mb + mi * 16 + lr) * 64 + s * 32 + quad * 8];
#pragma unroll
        for (int ni = 0; ni < 4; ++ni)
            bf[ni] = *(const short8*)&Wdt[(size_t)(d0 + wave * 64 + ni * 16 + lr) * 64 + s * 32 + quad * 8];
#pragma unroll
        for (int mi = 0; mi < 2; ++mi)
#pragma unroll
            for (int ni = 0; ni < 4; ++ni)
                acc[mi][ni] = __builtin_amdgcn_mfma_f32_16x16x32_bf16(
                    af[mi], bf[ni], acc[mi][ni], 0, 0, 0);
    }

#pragma unroll
    for (int ni = 0; ni < 4; ++ni) {
        const int cc = wave * 64 + ni * 16 + lr;
        const float bv = bias[d0 + cc];
#pragma unroll
        for (int mi = 0; mi < 2; ++mi)
#pragma unroll
            for (int r = 0; r < 4; ++r) {
                const float z = acc[mi][ni][r] + bv;
                const float spv = fmaxf(z, 0.f) + __logf(1.f + __expf(-fabsf(z)));
                dtile[mi * 16 + quad * 4 + r][cc] = spv;
            }
    }
}

// ---------------- scan pass 1: fused dt + per-chunk H[n] + dt-sum scalar --------
__global__ __launch_bounds__(256) void scan_p1(
    const unsigned short* __restrict__ sp64, const unsigned short* __restrict__ Wdt,
    const float* __restrict__ b_dt, const unsigned short* __restrict__ x_bf,
    const float* __restrict__ sp, const float* __restrict__ A_log,
    float* __restrict__ Dts, float* __restrict__ Hch)
{
    __shared__ float sB[CL][16];
    __shared__ float dtile[CL][260];
    const int tid = threadIdx.x;
    const int lane = tid & 63;
    const int wave = tid >> 6;
    const int lr = lane & 15;
    const int quad = lane >> 4;
    const int d0 = blockIdx.x * 256;
    const int d = d0 + tid;
    const int ck = blockIdx.y;
    const int b = blockIdx.z;
    const int mb = b * 1024 + ck * CL;

    dt_tile(sp64, Wdt, b_dt, mb, d0, lane, wave, lr, quad, dtile);

    if (tid < CL * 4) {
        int row = tid >> 2, q = (tid & 3) * 4;
        *(float4*)&sB[row][q] = *(const float4*)(sp + (size_t)(mb + row) * 96 + 64 + q);
    }
    float An2[16];
    {
        const float* al = A_log + d * 16;
#pragma unroll
        for (int j = 0; j < 16; j += 4) {
            float4 a4 = *(const float4*)(al + j);
            An2[j + 0] = -__expf(a4.x) * 1.44269504f;
            An2[j + 1] = -__expf(a4.y) * 1.44269504f;
            An2[j + 2] = -__expf(a4.z) * 1.44269504f;
            An2[j + 3] = -__expf(a4.w) * 1.44269504f;
        }
    }
    __syncthreads();

    float h[16];
#pragma unroll
    for (int n = 0; n < 16; ++n) h[n] = 0.f;
    float dts = 0.f;

    for (int l = 0; l < CL; ++l) {
        const size_t off = (size_t)(mb + l) * 2048 + d;
        const float dtv = dtile[l][tid];
        const float xv = bf2f(x_bf[off]);
        const float u = dtv * xv;
        dts += dtv;
        float4 B0 = *(const float4*)&sB[l][0];
        float4 B1 = *(const float4*)&sB[l][4];
        float4 B2 = *(const float4*)&sB[l][8];
        float4 B3 = *(const float4*)&sB[l][12];
        float Bv[16] = {B0.x, B0.y, B0.z, B0.w, B1.x, B1.y, B1.z, B1.w,
                        B2.x, B2.y, B2.z, B2.w, B3.x, B3.y, B3.z, B3.w};
#pragma unroll
        for (int n = 0; n < 16; ++n) {
            const float dA = __builtin_amdgcn_exp2f(dtv * An2[n]);
            h[n] = fmaf(dA, h[n], Bv[n] * u);
        }
    }

    const size_t cb = (size_t)(b * NCK + ck) * 2048 + d;
    Dts[cb] = dts;
    const size_t base = cb * 16;
#pragma unroll
    for (int j = 0; j < 16; j += 4)
        *(float4*)(Hch + base + j) = make_float4(h[j], h[j + 1], h[j + 2], h[j + 3]);
}

// ---------------- scan combine: serial over chunks; recompute P from dts ------
__global__ __launch_bounds__(256) void scan_combine(
    const float* __restrict__ Dts, const float* __restrict__ Hch,
    const float* __restrict__ A_log, float* __restrict__ Hin)
{
    const int flat = blockIdx.x * 256 + threadIdx.x;   // 2*2048*16
    const int dn = flat & 32767;
    const int b = flat >> 15;
    const int d = dn >> 4;
    const float An2 = -__expf(A_log[dn]) * 1.44269504f;
    float hin = 0.f;
#pragma unroll 4
    for (int ck = 0; ck < NCK; ++ck) {
        const size_t cb = (size_t)(b * NCK + ck) * 2048 + d;
        const float p = __builtin_amdgcn_exp2f(Dts[cb] * An2);
        const size_t a = ((size_t)(b * NCK + ck) << 15) + dn;
        const float hc = Hch[a];
        Hin[a] = hin;
        hin = fmaf(p, hin, hc);
    }
}

// ---------------- scan pass 2: fused dt + rescan with h_in + gating -> y_bf ----
__global__ __launch_bounds__(256) void scan_p2(
    const unsigned short* __restrict__ sp64, const unsigned short* __restrict__ Wdt,
    const float* __restrict__ b_dt, const unsigned short* __restrict__ x_bf,
    const float* __restrict__ gate, const float* __restrict__ sp,
    const float* __restrict__ A_log, const float* __restrict__ Dp,
    const float* __restrict__ Hin, unsigned short* __restrict__ y_bf)
{
    __shared__ float sBC[CL][32];
    __shared__ float dtile[CL][260];
    const int tid = threadIdx.x;
    const int lane = tid & 63;
    const int wave = tid >> 6;
    const int lr = lane & 15;
    const int quad = lane >> 4;
    const int d0 = blockIdx.x * 256;
    const int d = d0 + tid;
    const int ck = blockIdx.y;
    const int b = blockIdx.z;
    const int mb = b * 1024 + ck * CL;

    dt_tile(sp64, Wdt, b_dt, mb, d0, lane, wave, lr, quad, dtile);

    {
        int row = tid >> 3, q = (tid & 7) * 4;
        *(float4*)&sBC[row][q] = *(const float4*)(sp + (size_t)(mb + row) * 96 + 64 + q);
    }
    float An2[16];
    {
        const float* al = A_log + d * 16;
#pragma unroll
        for (int j = 0; j < 16; j += 4) {
            float4 a4 = *(const float4*)(al + j);
            An2[j + 0] = -__expf(a4.x) * 1.44269504f;
            An2[j + 1] = -__expf(a4.y) * 1.44269504f;
            An2[j + 2] = -__expf(a4.z) * 1.44269504f;
            An2[j + 3] = -__expf(a4.w) * 1.44269504f;
        }
    }
    float h[16];
    {
        const size_t base = ((size_t)(b * NCK + ck) * 2048 + d) * 16;
#pragma unroll
        for (int j = 0; j < 16; j += 4) {
            float4 hv = *(const float4*)(Hin + base + j);
            h[j] = hv.x; h[j + 1] = hv.y; h[j + 2] = hv.z; h[j + 3] = hv.w;
        }
    }
    const float Dv = Dp[d];
    __syncthreads();

    for (int l = 0; l < CL; ++l) {
        const size_t off = (size_t)(mb + l) * 2048 + d;
        const float dtv = dtile[l][tid];
        const float xv = bf2f(x_bf[off]);
        const float gv = gate[off];
        const float u = dtv * xv;
        float4 B0 = *(const float4*)&sBC[l][0];
        float4 B1 = *(const float4*)&sBC[l][4];
        float4 B2 = *(const float4*)&sBC[l][8];
        float4 B3 = *(const float4*)&sBC[l][12];
        float Bv[16] = {B0.x, B0.y, B0.z, B0.w, B1.x, B1.y, B1.z, B1.w,
                        B2.x, B2.y, B2.z, B2.w, B3.x, B3.y, B3.z, B3.w};
#pragma unroll
        for (int n = 0; n < 16; ++n) {
            const float dA = __builtin_amdgcn_exp2f(dtv * An2[n]);
            h[n] = fmaf(dA, h[n], Bv[n] * u);
        }
        float4 C0 = *(const float4*)&sBC[l][16];
        float4 C1 = *(const float4*)&sBC[l][20];
        float4 C2 = *(const float4*)&sBC[l][24];
        float4 C3 = *(const float4*)&sBC[l][28];
        float Cv[16] = {C0.x, C0.y, C0.z, C0.w, C1.x, C1.y, C1.z, C1.w,
                        C2.x, C2.y, C2.z, C2.w, C3.x, C3.y, C3.z, C3.w};
        float p = 0.f;
#pragma unroll
        for (int n = 0; n < 16; ++n)
            p = fmaf(h[n], Cv[n], p);
        y_bf[off] = f2bf(fmaf(xv, Dv, p) * siluf(gv));
    }
}

extern "C" void kernel_launch(void* const* d_in, const int* in_sizes, int n_in,
                              void* d_out, int out_size, void* d_ws, size_t ws_size,
                              hipStream_t stream)
{
    const float* hs     = (const float*)d_in[0];
    const float* W_in   = (const float*)d_in[1];
    const float* conv_w = (const float*)d_in[2];
    const float* conv_b = (const float*)d_in[3];
    const float* W_x    = (const float*)d_in[4];
    const float* W_dt   = (const float*)d_in[5];
    const float* b_dt   = (const float*)d_in[6];
    const float* A_log  = (const float*)d_in[7];
    const float* Dp     = (const float*)d_in[8];
    const float* W_out  = (const float*)d_in[9];
    float* out = (float*)d_out;

    // workspace (~78 MB live) with overlays (dtb slot now unused — dt fused into scans)
    float* ws    = (float*)d_ws;
    float* gate  = ws;                               // [2048 m][2048 d] f32
    float* dtb   = gate + (size_t)4194304;           // (unused)
    float* xpre  = dtb + (size_t)4194304;            // [2048 m][2048 d] f32 (dead after conv)
    float* ssm_p = xpre + (size_t)4194304;           // [2048 m][96] f32
    unsigned short* hs_bf    = (unsigned short*)(ssm_p + 196608);   // 2048*1024
    unsigned short* W_in_bf  = hs_bf + (size_t)2097152;             // 4096*1024
    unsigned short* W_out_bf = W_in_bf + (size_t)4194304;           // 1024*2048
    unsigned short* W_x_bf   = W_out_bf + (size_t)2097152;          // 96*2048
    unsigned short* W_dt_bf  = W_x_bf + (size_t)196608;             // 2048*64
    unsigned short* sp64_bf  = W_dt_bf + (size_t)131072;            // 2048*64
    unsigned short* x_bf     = sp64_bf + (size_t)131072;            // [2048 m][2048 d]
    float* Dts  = (float*)(x_bf + (size_t)4194304);   // [2*32][2048] dt-sums (0.5 MB)
    float* P1   = xpre;                               // overlay: ssm partials 16*2048*96
    float* Hin  = xpre;                               // overlay after reduce_ssm: 2*32*2048*16
    float* Hch  = xpre + (size_t)2097152;             // overlay
    float* Pout = gate;                               // overlay after scan_p2 (gate dead)
    unsigned short* y_bf = hs_bf;                     // overlay (hs_bf+W_in_bf dead)

    const int M = B_ * L_;  // 2048

    // 0. fused fp32 -> bf16 converts (hs, W_in, W_out, W_x, W_dt)
    cvt_all<<<(Q4 + 255) / 256, 256, 0, stream>>>(
        hs, W_in, W_out, W_x, W_dt, hs_bf, W_in_bf, W_out_bf, W_x_bf, W_dt_bf);

    // 1. proj GEMM: 128x128 fat-wave tile, BK=64 -> 512 blocks (XCD-swizzled), nt=16
    gemm128<4><<<dim3(4096 / 128, M / 128, 1), 256, 0, stream>>>(
        hs_bf, W_in_bf, xpre, 1024, 2048, 1024, 0, gate);

    // 2. conv + SiLU (m-major in via LDS stage) -> x_bf[m][d]
    conv_silu_kernel<<<dim3(D_ / 64, L_ / 64, B_), 256, 0, stream>>>(
        xpre, conv_w, conv_b, x_bf);

    // 3. ssm partials: P1[z][m][96] = x @ W_x^T (K-chunk 128, 16 splits, nt=2)
    gemm_ssm<<<dim3(1, M / 64, 16), 256, 0, stream>>>(
        x_bf, W_x_bf, P1, 2048, 96, 96, 128, 96, (size_t)2048 * 96);

    // 3b. reduce 16 partials -> ssm_p[m][96] + sp64_bf[m][64]
    reduce_ssm<<<(2048 * 24) / 256, 256, 0, stream>>>(P1, ssm_p, sp64_bf);

    // 4+5. scan with fused dt: pass1 -> combine -> pass2 (writes y_bf[m][d])
    scan_p1<<<dim3(D_ / 256, NCK, B_), 256, 0, stream>>>(
        sp64_bf, W_dt_bf, b_dt, x_bf, ssm_p, A_log, Dts, Hch);
    scan_combine<<<(B_ * D_ * 16) / 256, 256, 0, stream>>>(Dts, Hch, A_log, Hin);
    scan_p2<<<dim3(D_ / 256, NCK, B_), 256, 0, stream>>>(
        sp64_bf, W_dt_bf, b_dt, x_bf, gate, ssm_p, A_log, Dp, Hin, y_bf);

    // 6. out partials: 128x128 fat-wave, K-chunk 512, 4 splits -> 512 blocks (swizzled)
    gemm128<0><<<dim3(1024 / 128, M / 128, 4), 256, 0, stream>>>(
        y_bf, W_out_bf, Pout, 2048, 1024, 512, (size_t)2048 * 1024, nullptr);

    // 6b. reduce 4 partials -> out
    reduce_out<<<(2048 * 1024 / 4) / 256, 256, 0, stream>>>(Pout, out);
}